// Round 2
// baseline (2791.566 us; speedup 1.0000x reference)
//
#include <hip/hip_runtime.h>

#define NC    64      // channels C
#define NATTR 10      // node attrs
#define NH    64      // radial MLP hidden
#define NRAD  8       // radial features
#define TEB   128     // CSR positions per edge block
#define MPN   704     // f32 message floats per node

__device__ __forceinline__ float silu_f(float x) { return x / (1.0f + __expf(-x)); }

// RTNE pack of two f32 into bf16x2 (lo in low 16, hi in high 16)
__device__ __forceinline__ unsigned int pk_bf16(float lo, float hi)
{
    unsigned int ulo = __float_as_uint(lo);
    unsigned int uhi = __float_as_uint(hi);
    ulo = (ulo + 0x7FFFu + ((ulo >> 16) & 1u)) >> 16;
    uhi = (uhi + 0x7FFFu + ((uhi >> 16) & 1u)) & 0xFFFF0000u;
    return ulo | uhi;
}
#define BLO(u) __uint_as_float((u) << 16)
#define BHI(u) __uint_as_float((u) & 0xFFFF0000u)

// ---------------------------------------------------------------------------
// d_out layout (f32, out_size = N*512):
//   out_s : [0,      N*64 )   -- also CSR int scratch until out written
//   out_v : [N*64,   N*256)
//   sc_s  : [N*256,  N*320)   -- self-linear s scratch until sc_kernel
//   sc_v  : [N*320,  N*512)   -- self-linear v scratch until sc_kernel
// ws: m[N*704] f32 message accumulator (140.8 MB)
// ---------------------------------------------------------------------------

// ---------------- CSR build (scratch ints live in d_out's out region) ------
__global__ void hist_kernel(const int* __restrict__ rcv, int* __restrict__ deg, int E)
{
    int e = blockIdx.x * 256 + threadIdx.x;
    if (e < E) atomicAdd(&deg[rcv[e]], 1);
}

__global__ __launch_bounds__(256)
void scan_kernel(const int* __restrict__ deg, int* __restrict__ row_ptr, int N)
{
    __shared__ int sums[256];
    __shared__ int offs[257];
    const int t = threadIdx.x;
    const int chunk = (N + 255) / 256;
    int b = t * chunk, e = min(N, b + chunk);
    int s = 0;
    for (int k = b; k < e; k++) s += deg[k];
    sums[t] = s;
    __syncthreads();
    if (t == 0) {
        int run = 0;
        for (int i = 0; i < 256; i++) { offs[i] = run; run += sums[i]; }
        offs[256] = run;
    }
    __syncthreads();
    int run = offs[t];
    for (int k = b; k < e; k++) { row_ptr[k] = run; run += deg[k]; }
    if (t == 255) row_ptr[N] = offs[256];
}

__global__ void fill_kernel(const int* __restrict__ rcv, const int* __restrict__ row_ptr,
                            int* __restrict__ cursor, int* __restrict__ eidx, int E)
{
    int e = blockIdx.x * 256 + threadIdx.x;
    if (e < E) {
        int r = rcv[e];
        int pos = atomicAdd(&cursor[r], 1);
        eidx[row_ptr[r] + pos] = e;
    }
}

// ---------------- self linear: wave-per-node, 4 nodes/block ----------------
__global__ __launch_bounds__(256)
void self_kernel(const float* __restrict__ fs, const float* __restrict__ fv,
                 const float* __restrict__ Wes, const float* __restrict__ Wev,
                 float* __restrict__ out, int N)
{
    __shared__ float s_l[4][NC];
    __shared__ float v_l[4][3][NC];
    const int t = threadIdx.x, wv = t >> 6, lane = t & 63;
    const int n = blockIdx.x * 4 + wv;

    if (n < N) {
        s_l[wv][lane] = fs[(size_t)n * NC + lane];
        v_l[wv][0][lane] = fv[(size_t)n * NC * 3 + lane * 3 + 0];
        v_l[wv][1][lane] = fv[(size_t)n * NC * 3 + lane * 3 + 1];
        v_l[wv][2][lane] = fv[(size_t)n * NC * 3 + lane * 3 + 2];
    }
    __syncthreads();
    if (n >= N) return;

    const int d = lane;
    float a = 0.f, bx = 0.f, by = 0.f, bz = 0.f;
    #pragma unroll 8
    for (int c = 0; c < NC; c++) {
        float ws = Wes[c * NC + d];
        float wvv = Wev[c * NC + d];
        a  += s_l[wv][c] * ws;
        bx += v_l[wv][0][c] * wvv;
        by += v_l[wv][1][c] * wvv;
        bz += v_l[wv][2][c] * wvv;
    }
    out[(size_t)N * 256 + (size_t)n * NC + d]            = a  * 0.125f;
    out[(size_t)N * 320 + (size_t)n * 192 +       d]     = bx * 0.125f;
    out[(size_t)N * 320 + (size_t)n * 192 +  64 + d]     = by * 0.125f;
    out[(size_t)N * 320 + (size_t)n * 192 + 128 + d]     = bz * 0.125f;
}

// ---------------------------------------------------------------------------
// Edge kernel: 128 CSR positions per 128-thread block.
// Phase 1: thread-per-edge radial MLP layers 1-3; h3 packed bf16x2 -> LDS
//   (18.4 KB instead of 34.8 KB -> 7 blocks/CU, 14 waves/CU).
// Phase 2: wave-per-edge layer 4 + tensor product in two passes; W4 column
//   slices held as packed bf16x2 (pass A 64 uints, pass B 96 uints) so they
//   are truly register-resident (f32 arrays got rematerialized as per-
//   iteration global loads at VGPR=120). Gathers software-pipelined depth-2.
// m per-node layout: [0,64) p1 | [64,128) p2 | 128 + x*192 + {0:p3,64:p4,128:p5}
// ---------------------------------------------------------------------------
__global__ __launch_bounds__(128, 3)
void edge_kernel(const float* __restrict__ ef, const float* __restrict__ sh0,
                 const float* __restrict__ sh1,
                 const int* __restrict__ snd, const int* __restrict__ rcv,
                 const float* __restrict__ W1, const float* __restrict__ W2,
                 const float* __restrict__ W3, const float* __restrict__ W4,
                 const float* __restrict__ s_st, const float* __restrict__ v_st,
                 const int* __restrict__ eidx,
                 float* __restrict__ m, int E)
{
    __shared__ unsigned int h_l[TEB][36];   // 32 packed bf16x2 + pad (144B rows, 16B-aligned)
    __shared__ float sh1_l[TEB][3];
    __shared__ float sh0_l[TEB];
    __shared__ int   snd_l[TEB];
    __shared__ int   rcv_l[TEB];

    const int t = threadIdx.x;
    const int p0 = blockIdx.x * TEB;

    // ---------------- phase 1 ----------------
    {
        int p = p0 + t;
        bool valid = p < E;
        int e = valid ? eidx[p] : 0;
        snd_l[t] = valid ? snd[e] : 0;
        rcv_l[t] = valid ? rcv[e] : -1;
        sh0_l[t] = valid ? sh0[e] : 0.f;
        sh1_l[t][0] = valid ? sh1[(size_t)e * 3 + 0] : 0.f;
        sh1_l[t][1] = valid ? sh1[(size_t)e * 3 + 1] : 0.f;
        sh1_l[t][2] = valid ? sh1[(size_t)e * 3 + 2] : 0.f;

        float x[NRAD];
        #pragma unroll
        for (int r = 0; r < NRAD; r++)
            x[r] = valid ? ef[(size_t)e * NRAD + r] : 0.f;

        // layer 1: 8 -> 64 (h1 in registers)
        float h1[NH];
        #pragma unroll
        for (int j = 0; j < NH; j++) {
            float a = 0.f;
            #pragma unroll
            for (int r = 0; r < NRAD; r++) a += x[r] * W1[r * NH + j];
            h1[j] = silu_f(a * 0.35355339059327373f);   // 1/sqrt(8)
        }

        // layer 2: h1(regs) -> h2(regs), j tiled by 4
        float h2[NH];
        for (int jt = 0; jt < 16; jt++) {
            float a0 = 0.f, a1 = 0.f, a2 = 0.f, a3 = 0.f;
            #pragma unroll
            for (int c = 0; c < NH; c++) {
                float hv = h1[c];
                const float* wr = W2 + c * NH + jt * 4;
                a0 += hv * wr[0]; a1 += hv * wr[1];
                a2 += hv * wr[2]; a3 += hv * wr[3];
            }
            h2[jt * 4 + 0] = silu_f(a0 * 0.125f);
            h2[jt * 4 + 1] = silu_f(a1 * 0.125f);
            h2[jt * 4 + 2] = silu_f(a2 * 0.125f);
            h2[jt * 4 + 3] = silu_f(a3 * 0.125f);
        }
        // layer 3: h2(regs) -> h3 packed bf16x2 -> LDS
        for (int jt = 0; jt < 16; jt++) {
            float a0 = 0.f, a1 = 0.f, a2 = 0.f, a3 = 0.f;
            #pragma unroll
            for (int c = 0; c < NH; c++) {
                float hv = h2[c];
                const float* wr = W3 + c * NH + jt * 4;
                a0 += hv * wr[0]; a1 += hv * wr[1];
                a2 += hv * wr[2]; a3 += hv * wr[3];
            }
            h_l[t][jt * 2 + 0] = pk_bf16(silu_f(a0 * 0.125f), silu_f(a1 * 0.125f));
            h_l[t][jt * 2 + 1] = pk_bf16(silu_f(a2 * 0.125f), silu_f(a3 * 0.125f));
        }
    }
    __syncthreads();

    // ---------------- phase 2 ----------------
    const int wv = t >> 6, lane = t & 63;
    const int base_pos = wv * 64;

    // sender index of edge i lives in lane i; broadcast with v_readlane so
    // prefetch address computation has no LDS dependency
    const int v_sd = snd_l[base_pos + lane];

    // ---- pass A: slices 0 (p1) and 2 (p3); one se gather per edge --------
    {
        unsigned int WA[32], WC[32];
        #pragma unroll
        for (int q = 0; q < 32; q++) {
            WA[q] = pk_bf16(W4[(2 * q) * 320 + lane],       W4[(2 * q + 1) * 320 + lane]);
            WC[q] = pk_bf16(W4[(2 * q) * 320 + 128 + lane], W4[(2 * q + 1) * 320 + 128 + lane]);
        }
        float g[4];
        {
            int sd0 = __builtin_amdgcn_readlane(v_sd, 0);
            int sd1 = __builtin_amdgcn_readlane(v_sd, 1);
            g[0] = s_st[(size_t)sd0 * NC + lane];
            g[1] = s_st[(size_t)sd1 * NC + lane];
        }
        #pragma unroll 2
        for (int ei = 0; ei < 64; ei++) {
            {   // depth-2 prefetch of se for edge ei+2
                int pn = ei + 2 > 63 ? 63 : ei + 2;
                int sdn = __builtin_amdgcn_readlane(v_sd, pn);
                g[(ei + 2) & 3] = s_st[(size_t)sdn * NC + lane];
            }
            const int pos = base_pos + ei;
            const int r = rcv_l[pos];
            if (r >= 0) {
                const uint4* hp = (const uint4*)(&h_l[pos][0]);
                float a = 0.f, b = 0.f;
                #pragma unroll
                for (int q8 = 0; q8 < 8; q8++) {
                    uint4 hu = hp[q8];
                    unsigned int u, wa, wc; float hl, hh;
                    u = hu.x; wa = WA[q8 * 4 + 0]; wc = WC[q8 * 4 + 0];
                    hl = BLO(u); hh = BHI(u);
                    a += hl * BLO(wa); a += hh * BHI(wa);
                    b += hl * BLO(wc); b += hh * BHI(wc);
                    u = hu.y; wa = WA[q8 * 4 + 1]; wc = WC[q8 * 4 + 1];
                    hl = BLO(u); hh = BHI(u);
                    a += hl * BLO(wa); a += hh * BHI(wa);
                    b += hl * BLO(wc); b += hh * BHI(wc);
                    u = hu.z; wa = WA[q8 * 4 + 2]; wc = WC[q8 * 4 + 2];
                    hl = BLO(u); hh = BHI(u);
                    a += hl * BLO(wa); a += hh * BHI(wa);
                    b += hl * BLO(wc); b += hh * BHI(wc);
                    u = hu.w; wa = WA[q8 * 4 + 3]; wc = WC[q8 * 4 + 3];
                    hl = BLO(u); hh = BHI(u);
                    a += hl * BLO(wa); a += hh * BHI(wa);
                    b += hl * BLO(wc); b += hh * BHI(wc);
                }
                float w1w = a * 0.125f;  // 1/sqrt(64)
                float w3w = b * 0.125f;
                float se  = g[ei & 3];
                float s0  = sh0_l[pos];
                float shx = sh1_l[pos][0], shy = sh1_l[pos][1], shz = sh1_l[pos][2];
                float* mb = m + (size_t)r * MPN;

                unsafeAtomicAdd(mb + lane, w1w * se * s0);                       // p1
                float t3 = w3w * se;                                             // p3
                unsafeAtomicAdd(mb + 128 + lane,       t3 * shx);
                unsafeAtomicAdd(mb + 128 + 192 + lane, t3 * shy);
                unsafeAtomicAdd(mb + 128 + 384 + lane, t3 * shz);
            }
        }
    }

    // ---- pass B: slices 1 (p2), 3 (p4), 4 (p5); one v gather per edge ----
    {
        unsigned int WB[32], WD[32], WE[32];
        #pragma unroll
        for (int q = 0; q < 32; q++) {
            WB[q] = pk_bf16(W4[(2 * q) * 320 +  64 + lane], W4[(2 * q + 1) * 320 +  64 + lane]);
            WD[q] = pk_bf16(W4[(2 * q) * 320 + 192 + lane], W4[(2 * q + 1) * 320 + 192 + lane]);
            WE[q] = pk_bf16(W4[(2 * q) * 320 + 256 + lane], W4[(2 * q + 1) * 320 + 256 + lane]);
        }
        float gx[4], gy[4], gz[4];
        {
            int sd0 = __builtin_amdgcn_readlane(v_sd, 0);
            int sd1 = __builtin_amdgcn_readlane(v_sd, 1);
            size_t sb0 = (size_t)sd0 * 192, sb1 = (size_t)sd1 * 192;
            gx[0] = v_st[sb0 + lane]; gy[0] = v_st[sb0 + 64 + lane]; gz[0] = v_st[sb0 + 128 + lane];
            gx[1] = v_st[sb1 + lane]; gy[1] = v_st[sb1 + 64 + lane]; gz[1] = v_st[sb1 + 128 + lane];
        }
        #pragma unroll 2
        for (int ei = 0; ei < 64; ei++) {
            {   // depth-2 prefetch of v for edge ei+2
                int pn = ei + 2 > 63 ? 63 : ei + 2;
                int sdn = __builtin_amdgcn_readlane(v_sd, pn);
                size_t sb = (size_t)sdn * 192;
                gx[(ei + 2) & 3] = v_st[sb + lane];
                gy[(ei + 2) & 3] = v_st[sb + 64 + lane];
                gz[(ei + 2) & 3] = v_st[sb + 128 + lane];
            }
            const int pos = base_pos + ei;
            const int r = rcv_l[pos];
            if (r >= 0) {
                const uint4* hp = (const uint4*)(&h_l[pos][0]);
                float a = 0.f, b = 0.f, c = 0.f;
                #pragma unroll
                for (int q8 = 0; q8 < 8; q8++) {
                    uint4 hu = hp[q8];
                    unsigned int u, wb, wd, we; float hl, hh;
                    u = hu.x; wb = WB[q8 * 4 + 0]; wd = WD[q8 * 4 + 0]; we = WE[q8 * 4 + 0];
                    hl = BLO(u); hh = BHI(u);
                    a += hl * BLO(wb); a += hh * BHI(wb);
                    b += hl * BLO(wd); b += hh * BHI(wd);
                    c += hl * BLO(we); c += hh * BHI(we);
                    u = hu.y; wb = WB[q8 * 4 + 1]; wd = WD[q8 * 4 + 1]; we = WE[q8 * 4 + 1];
                    hl = BLO(u); hh = BHI(u);
                    a += hl * BLO(wb); a += hh * BHI(wb);
                    b += hl * BLO(wd); b += hh * BHI(wd);
                    c += hl * BLO(we); c += hh * BHI(we);
                    u = hu.z; wb = WB[q8 * 4 + 2]; wd = WD[q8 * 4 + 2]; we = WE[q8 * 4 + 2];
                    hl = BLO(u); hh = BHI(u);
                    a += hl * BLO(wb); a += hh * BHI(wb);
                    b += hl * BLO(wd); b += hh * BHI(wd);
                    c += hl * BLO(we); c += hh * BHI(we);
                    u = hu.w; wb = WB[q8 * 4 + 3]; wd = WD[q8 * 4 + 3]; we = WE[q8 * 4 + 3];
                    hl = BLO(u); hh = BHI(u);
                    a += hl * BLO(wb); a += hh * BHI(wb);
                    b += hl * BLO(wd); b += hh * BHI(wd);
                    c += hl * BLO(we); c += hh * BHI(we);
                }
                float w2w = a * 0.125f;
                float w4w = b * 0.125f;
                float w5w = c * 0.125f;
                float vx = gx[ei & 3], vy = gy[ei & 3], vz = gz[ei & 3];
                float s0  = sh0_l[pos];
                float shx = sh1_l[pos][0], shy = sh1_l[pos][1], shz = sh1_l[pos][2];
                float* mb = m + (size_t)r * MPN;

                float dot = vx * shx + vy * shy + vz * shz;                      // p2
                unsafeAtomicAdd(mb + 64 + lane, w2w * dot * 0.5773502691896258f);
                float w4s = w4w * s0;                                            // p4
                unsafeAtomicAdd(mb + 128 + 64 + lane,       w4s * vx);
                unsafeAtomicAdd(mb + 128 + 192 + 64 + lane, w4s * vy);
                unsafeAtomicAdd(mb + 128 + 384 + 64 + lane, w4s * vz);
                float w5s = w5w * 0.7071067811865476f;                           // p5
                unsafeAtomicAdd(mb + 128 + 128 + lane,       w5s * (vy * shz - vz * shy));
                unsafeAtomicAdd(mb + 128 + 192 + 128 + lane, w5s * (vz * shx - vx * shz));
                unsafeAtomicAdd(mb + 128 + 384 + 128 + lane, w5s * (vx * shy - vy * shx));
            }
        }
    }
}

// ---------------------------------------------------------------------------
// Skip-connection as tiled GEMM: C[64n x 64d] per block, A[n][k]=feat*attr
// built on the fly (coalesced: lanes sweep k), B-tile staged, 4x4 register
// blocking. blockIdx.y = part (0: scalar->sc_s, 1..3: vector x -> sc_v).
// ---------------------------------------------------------------------------
__global__ __launch_bounds__(256)
void sc_kernel(const float* __restrict__ attrs, const float* __restrict__ fs,
               const float* __restrict__ fv,
               const float* __restrict__ Wss, const float* __restrict__ Wsv,
               float* __restrict__ out, int N)
{
    __shared__ float At[64][68];   // [kk][n]
    __shared__ float Bt[64][68];   // [kk][d]

    const int part = blockIdx.y;
    const int n0 = blockIdx.x * 64;
    const int t = threadIdx.x;
    const int tn = t & 15, td = t >> 4;
    const float* W = (part == 0) ? Wss : Wsv;
    const int x = part - 1;

    float acc[4][4];
    #pragma unroll
    for (int i = 0; i < 4; i++)
        #pragma unroll
        for (int j = 0; j < 4; j++) acc[i][j] = 0.f;

    for (int kt = 0; kt < 10; kt++) {
        __syncthreads();
        // build A-tile: lanes sweep kk (coalesced along k), 8-way LDS write
        // conflict on At[kk][n] is negligible (16 b32 writes/thread)
        for (int i = t; i < 4096; i += 256) {
            int n = i >> 6, kk = i & 63;
            int k = kt * 64 + kk;
            int c = k / 10, am = k - c * 10;
            int ng = n0 + n;
            float v = 0.f;
            if (ng < N) {
                float f = (part == 0) ? fs[(size_t)ng * 64 + c]
                                      : fv[((size_t)ng * 64 + c) * 3 + x];
                v = f * attrs[(size_t)ng * 10 + am];
            }
            At[kk][n] = v;
        }
        // load B-tile (coalesced in d)
        for (int i = t; i < 4096; i += 256) {
            int kk = i >> 6, d = i & 63;
            Bt[kk][d] = W[(size_t)(kt * 64 + kk) * 64 + d];
        }
        __syncthreads();
        #pragma unroll 8
        for (int kk = 0; kk < 64; kk++) {
            float a4[4], b4[4];
            #pragma unroll
            for (int i = 0; i < 4; i++) a4[i] = At[kk][tn * 4 + i];
            #pragma unroll
            for (int j = 0; j < 4; j++) b4[j] = Bt[kk][td * 4 + j];
            #pragma unroll
            for (int i = 0; i < 4; i++)
                #pragma unroll
                for (int j = 0; j < 4; j++) acc[i][j] += a4[i] * b4[j];
        }
    }

    const float inv_sc = 0.03952847075210474f;  // 1/sqrt(640)
    #pragma unroll
    for (int i = 0; i < 4; i++) {
        int ng = n0 + tn * 4 + i;
        if (ng >= N) continue;
        #pragma unroll
        for (int j = 0; j < 4; j++) {
            int d = td * 4 + j;
            float v = acc[i][j] * inv_sc;
            if (part == 0) out[(size_t)N * 256 + (size_t)ng * 64 + d] = v;
            else           out[(size_t)N * 320 + (size_t)ng * 192 + d * 3 + x] = v;
        }
    }
}

// ---------------------------------------------------------------------------
// Output linear as tiled GEMM over m. blockIdx.y = part (0: scalar k=128,
// 1..3: vector x, k=192). A-tile reads coalesced (lanes sweep kk).
// ---------------------------------------------------------------------------
__global__ __launch_bounds__(256)
void outlin_kernel(const float* __restrict__ m,
                   const float* __restrict__ Wos, const float* __restrict__ Wov,
                   float* __restrict__ out, int N)
{
    __shared__ float At[64][68];
    __shared__ float Bt[64][68];

    const int part = blockIdx.y;
    const int n0 = blockIdx.x * 64;
    const int t = threadIdx.x;
    const int tn = t & 15, td = t >> 4;
    const int x = part - 1;
    const int ntiles = (part == 0) ? 2 : 3;
    const int aoff = (part == 0) ? 0 : 128 + x * 192;
    const float* W = (part == 0) ? Wos : Wov;

    float acc[4][4];
    #pragma unroll
    for (int i = 0; i < 4; i++)
        #pragma unroll
        for (int j = 0; j < 4; j++) acc[i][j] = 0.f;

    for (int kt = 0; kt < ntiles; kt++) {
        __syncthreads();
        for (int i = t; i < 4096; i += 256) {
            int n = i >> 6, kk = i & 63;
            int ng = n0 + n;
            At[kk][n] = (ng < N) ? m[(size_t)ng * MPN + aoff + kt * 64 + kk] : 0.f;
        }
        for (int i = t; i < 4096; i += 256) {
            int kk = i >> 6, d = i & 63;
            Bt[kk][d] = W[(size_t)(kt * 64 + kk) * 64 + d];
        }
        __syncthreads();
        #pragma unroll 8
        for (int kk = 0; kk < 64; kk++) {
            float a4[4], b4[4];
            #pragma unroll
            for (int i = 0; i < 4; i++) a4[i] = At[kk][tn * 4 + i];
            #pragma unroll
            for (int j = 0; j < 4; j++) b4[j] = Bt[kk][td * 4 + j];
            #pragma unroll
            for (int i = 0; i < 4; i++)
                #pragma unroll
                for (int j = 0; j < 4; j++) acc[i][j] += a4[i] * b4[j];
        }
    }

    const float scale = (part == 0) ? 0.005524271728019903f    // 1/(sqrt(128)*16)
                                    : 0.004510527174164819f;   // 1/(sqrt(192)*16)
    #pragma unroll
    for (int i = 0; i < 4; i++) {
        int ng = n0 + tn * 4 + i;
        if (ng >= N) continue;
        #pragma unroll
        for (int j = 0; j < 4; j++) {
            int d = td * 4 + j;
            float v = acc[i][j] * scale;
            if (part == 0) out[(size_t)ng * 64 + d] = v;
            else           out[(size_t)N * 64 + (size_t)ng * 192 + d * 3 + x] = v;
        }
    }
}

// ---------------------------------------------------------------------------
extern "C" void kernel_launch(void* const* d_in, const int* in_sizes, int n_in,
                              void* d_out, int out_size, void* d_ws, size_t ws_size,
                              hipStream_t stream)
{
    const float* attrs = (const float*)d_in[0];
    const float* fs    = (const float*)d_in[1];
    const float* fv    = (const float*)d_in[2];
    const float* sh0   = (const float*)d_in[3];
    const float* sh1   = (const float*)d_in[4];
    const float* ef    = (const float*)d_in[5];
    const int*   snd   = (const int*)d_in[6];
    const int*   rcv   = (const int*)d_in[7];
    const float* Wss   = (const float*)d_in[8];
    const float* Wsv   = (const float*)d_in[9];
    const float* Wes   = (const float*)d_in[10];
    const float* Wev   = (const float*)d_in[11];
    const float* W1    = (const float*)d_in[12];
    const float* W2    = (const float*)d_in[13];
    const float* W3    = (const float*)d_in[14];
    const float* W4    = (const float*)d_in[15];
    const float* Wos   = (const float*)d_in[16];
    const float* Wov   = (const float*)d_in[17];

    const int N = in_sizes[0] / NATTR;   // 50000
    const int E = in_sizes[6];           // 320000

    float* out = (float*)d_out;
    const float* s_st = out + (size_t)N * 256;  // self-linear s scratch
    const float* v_st = out + (size_t)N * 320;  // self-linear v scratch

    // CSR int scratch in d_out's out region (overwritten later by outlin)
    int* deg     = (int*)d_out;
    int* cursor  = deg + N;
    int* row_ptr = cursor + N;
    int* eidx    = row_ptr + N + 1;

    float* m = (float*)d_ws;             // N*704 f32 = 140.8 MB (fits: round-4)

    hipMemsetAsync(deg, 0, (size_t)2 * N * sizeof(int), stream);
    hipMemsetAsync(m, 0, (size_t)N * MPN * sizeof(float), stream);

    const int eb = (E + 255) / 256;
    hist_kernel<<<eb, 256, 0, stream>>>(rcv, deg, E);
    scan_kernel<<<1, 256, 0, stream>>>(deg, row_ptr, N);
    fill_kernel<<<eb, 256, 0, stream>>>(rcv, row_ptr, cursor, eidx, E);

    self_kernel<<<(N + 3) / 4, 256, 0, stream>>>(fs, fv, Wes, Wev, out, N);

    const int nbe = (E + TEB - 1) / TEB;
    edge_kernel<<<nbe, 128, 0, stream>>>(ef, sh0, sh1, snd, rcv,
                                         W1, W2, W3, W4, s_st, v_st,
                                         eidx, m, E);

    dim3 g_out((N + 63) / 64, 4);
    outlin_kernel<<<g_out, 256, 0, stream>>>(m, Wos, Wov, out, N);

    dim3 g_sc((N + 63) / 64, 4);
    sc_kernel<<<g_sc, 256, 0, stream>>>(attrs, fs, fv, Wss, Wsv, out, N);
}

// Round 4
// 1820.458 us; speedup vs baseline: 1.5334x; 1.5334x over previous
//
#include <hip/hip_runtime.h>

#define NC    64      // channels C
#define NATTR 10      // node attrs
#define NH    64      // radial MLP hidden
#define NRAD  8       // radial features
#define TEB   128     // CSR positions per edge block
#define MPN   704     // f32 message floats per node

__device__ __forceinline__ float silu_f(float x) { return x / (1.0f + __expf(-x)); }

// RTNE pack of two f32 into bf16x2 (lo in low 16, hi in high 16)
__device__ __forceinline__ unsigned int pk_bf16(float lo, float hi)
{
    unsigned int ulo = __float_as_uint(lo);
    unsigned int uhi = __float_as_uint(hi);
    ulo = (ulo + 0x7FFFu + ((ulo >> 16) & 1u)) >> 16;
    uhi = (uhi + 0x7FFFu + ((uhi >> 16) & 1u)) & 0xFFFF0000u;
    return ulo | uhi;
}
#define BLO(u) __uint_as_float((u) << 16)
#define BHI(u) __uint_as_float((u) & 0xFFFF0000u)

// dual dot-product of one packed-bf16 h row (32 uints = 64 values) against
// two packed-bf16 weight columns held in registers. All indices static after
// unroll -> arrays stay in VGPRs.
__device__ __forceinline__ void dot2_bf16(const uint4* hp,
    const unsigned int (&Wa)[32], const unsigned int (&Wb)[32],
    float& ra, float& rb)
{
    float a = 0.f, b = 0.f;
    #pragma unroll
    for (int q8 = 0; q8 < 8; q8++) {
        uint4 hu = hp[q8];
        unsigned int hw[4] = {hu.x, hu.y, hu.z, hu.w};
        #pragma unroll
        for (int k = 0; k < 4; k++) {
            unsigned int u = hw[k];
            unsigned int wa = Wa[q8 * 4 + k], wb = Wb[q8 * 4 + k];
            float hl = BLO(u), hh = BHI(u);
            a += hl * BLO(wa) + hh * BHI(wa);
            b += hl * BLO(wb) + hh * BHI(wb);
        }
    }
    ra = a; rb = b;
}

__device__ __forceinline__ float dot1_bf16(const uint4* hp,
    const unsigned int (&Wa)[32])
{
    float a = 0.f;
    #pragma unroll
    for (int q8 = 0; q8 < 8; q8++) {
        uint4 hu = hp[q8];
        unsigned int hw[4] = {hu.x, hu.y, hu.z, hu.w};
        #pragma unroll
        for (int k = 0; k < 4; k++) {
            unsigned int u = hw[k];
            unsigned int wa = Wa[q8 * 4 + k];
            a += BLO(u) * BLO(wa) + BHI(u) * BHI(wa);
        }
    }
    return a;
}

// ---------------------------------------------------------------------------
// d_out layout (f32, out_size = N*512):
//   out_s : [0,      N*64 )   -- also CSR int scratch until out written
//   out_v : [N*64,   N*256)
//   sc_s  : [N*256,  N*320)   -- self-linear s scratch until sc_kernel
//   sc_v  : [N*320,  N*512)   -- self-linear v scratch until sc_kernel
// ws: m[N*704] f32 message accumulator (140.8 MB)
// ---------------------------------------------------------------------------

// ---------------- CSR build (scratch ints live in d_out's out region) ------
__global__ void hist_kernel(const int* __restrict__ rcv, int* __restrict__ deg, int E)
{
    int e = blockIdx.x * 256 + threadIdx.x;
    if (e < E) atomicAdd(&deg[rcv[e]], 1);
}

__global__ __launch_bounds__(256)
void scan_kernel(const int* __restrict__ deg, int* __restrict__ row_ptr, int N)
{
    __shared__ int sums[256];
    __shared__ int offs[257];
    const int t = threadIdx.x;
    const int chunk = (N + 255) / 256;
    int b = t * chunk, e = min(N, b + chunk);
    int s = 0;
    for (int k = b; k < e; k++) s += deg[k];
    sums[t] = s;
    __syncthreads();
    if (t == 0) {
        int run = 0;
        for (int i = 0; i < 256; i++) { offs[i] = run; run += sums[i]; }
        offs[256] = run;
    }
    __syncthreads();
    int run = offs[t];
    for (int k = b; k < e; k++) { row_ptr[k] = run; run += deg[k]; }
    if (t == 255) row_ptr[N] = offs[256];
}

__global__ void fill_kernel(const int* __restrict__ rcv, const int* __restrict__ row_ptr,
                            int* __restrict__ cursor, int* __restrict__ eidx, int E)
{
    int e = blockIdx.x * 256 + threadIdx.x;
    if (e < E) {
        int r = rcv[e];
        int pos = atomicAdd(&cursor[r], 1);
        eidx[row_ptr[r] + pos] = e;
    }
}

// ---------------- self linear: wave-per-node, 4 nodes/block ----------------
__global__ __launch_bounds__(256)
void self_kernel(const float* __restrict__ fs, const float* __restrict__ fv,
                 const float* __restrict__ Wes, const float* __restrict__ Wev,
                 float* __restrict__ out, int N)
{
    __shared__ float s_l[4][NC];
    __shared__ float v_l[4][3][NC];
    const int t = threadIdx.x, wv = t >> 6, lane = t & 63;
    const int n = blockIdx.x * 4 + wv;

    if (n < N) {
        s_l[wv][lane] = fs[(size_t)n * NC + lane];
        v_l[wv][0][lane] = fv[(size_t)n * NC * 3 + lane * 3 + 0];
        v_l[wv][1][lane] = fv[(size_t)n * NC * 3 + lane * 3 + 1];
        v_l[wv][2][lane] = fv[(size_t)n * NC * 3 + lane * 3 + 2];
    }
    __syncthreads();
    if (n >= N) return;

    const int d = lane;
    float a = 0.f, bx = 0.f, by = 0.f, bz = 0.f;
    #pragma unroll 8
    for (int c = 0; c < NC; c++) {
        float ws = Wes[c * NC + d];
        float wvv = Wev[c * NC + d];
        a  += s_l[wv][c] * ws;
        bx += v_l[wv][0][c] * wvv;
        by += v_l[wv][1][c] * wvv;
        bz += v_l[wv][2][c] * wvv;
    }
    out[(size_t)N * 256 + (size_t)n * NC + d]            = a  * 0.125f;
    out[(size_t)N * 320 + (size_t)n * 192 +       d]     = bx * 0.125f;
    out[(size_t)N * 320 + (size_t)n * 192 +  64 + d]     = by * 0.125f;
    out[(size_t)N * 320 + (size_t)n * 192 + 128 + d]     = bz * 0.125f;
}

// ---------------------------------------------------------------------------
// Edge kernel: 128 CSR positions per 128-thread block.
// Phase 1: thread-per-edge radial MLP; h1 f32 regs -> h2 PACKED bf16 in 32
//   uint regs (avoids 128-f32 dual liveness that spilled in r2) -> h3 packed
//   bf16x2 -> LDS (21.5 KB total -> 7 blocks/CU).
// Phase 2: wave-per-edge layer 4 + tensor product, THREE passes so every
//   register W-set is <= 64 packed uints (empirically spill-free):
//     A : slices {0,2} p1,p3 -- se gather
//     B1: slices {1,3} p2,p4 -- v gather
//     B2: slice  {4}   p5    -- v gather
//   Prefetch via NAMED double-buffer scalars (depth 2, no arrays -> no
//   runtime indexing -> no scratch). CSR receiver runs accumulate in
//   registers and flush atomics only on receiver change (~6x fewer atomics).
// m per-node layout: [0,64) p1 | [64,128) p2 | 128 + x*192 + {0:p3,64:p4,128:p5}
// ---------------------------------------------------------------------------
__global__ __launch_bounds__(128, 3)
void edge_kernel(const float* __restrict__ ef, const float* __restrict__ sh0,
                 const float* __restrict__ sh1,
                 const int* __restrict__ snd, const int* __restrict__ rcv,
                 const float* __restrict__ W1, const float* __restrict__ W2,
                 const float* __restrict__ W3, const float* __restrict__ W4,
                 const float* __restrict__ s_st, const float* __restrict__ v_st,
                 const int* __restrict__ eidx,
                 float* __restrict__ m, int E)
{
    __shared__ unsigned int h_l[TEB][36];   // 32 packed bf16x2 + pad (144B rows)
    __shared__ float sh1_l[TEB][3];
    __shared__ float sh0_l[TEB];
    __shared__ int   snd_l[TEB];
    __shared__ int   rcv_l[TEB];

    const int t = threadIdx.x;
    const int p0 = blockIdx.x * TEB;

    // ---------------- phase 1 ----------------
    {
        int p = p0 + t;
        bool valid = p < E;
        int e = valid ? eidx[p] : 0;
        snd_l[t] = valid ? snd[e] : 0;
        rcv_l[t] = valid ? rcv[e] : -1;
        sh0_l[t] = valid ? sh0[e] : 0.f;
        sh1_l[t][0] = valid ? sh1[(size_t)e * 3 + 0] : 0.f;
        sh1_l[t][1] = valid ? sh1[(size_t)e * 3 + 1] : 0.f;
        sh1_l[t][2] = valid ? sh1[(size_t)e * 3 + 2] : 0.f;

        float x[NRAD];
        #pragma unroll
        for (int r = 0; r < NRAD; r++)
            x[r] = valid ? ef[(size_t)e * NRAD + r] : 0.f;

        // layer 1: 8 -> 64 (h1 in registers)
        float h1[NH];
        #pragma unroll
        for (int j = 0; j < NH; j++) {
            float a = 0.f;
            #pragma unroll
            for (int r = 0; r < NRAD; r++) a += x[r] * W1[r * NH + j];
            h1[j] = silu_f(a * 0.35355339059327373f);   // 1/sqrt(8)
        }

        // layer 2: h1(f32 regs) -> h2 packed bf16 (32 uint regs)
        unsigned int h2p[32];
        for (int jt = 0; jt < 16; jt++) {
            float a0 = 0.f, a1 = 0.f, a2 = 0.f, a3 = 0.f;
            #pragma unroll
            for (int c = 0; c < NH; c++) {
                float hv = h1[c];
                const float* wr = W2 + c * NH + jt * 4;
                a0 += hv * wr[0]; a1 += hv * wr[1];
                a2 += hv * wr[2]; a3 += hv * wr[3];
            }
            h2p[jt * 2 + 0] = pk_bf16(silu_f(a0 * 0.125f), silu_f(a1 * 0.125f));
            h2p[jt * 2 + 1] = pk_bf16(silu_f(a2 * 0.125f), silu_f(a3 * 0.125f));
        }
        // layer 3: h2 packed -> h3 packed -> LDS (h1 dead; regs reused)
        for (int jt = 0; jt < 16; jt++) {
            float a0 = 0.f, a1 = 0.f, a2 = 0.f, a3 = 0.f;
            #pragma unroll
            for (int cp = 0; cp < 32; cp++) {
                unsigned int u = h2p[cp];
                float hl = BLO(u), hh = BHI(u);
                const float* wr0 = W3 + (2 * cp) * NH + jt * 4;
                const float* wr1 = W3 + (2 * cp + 1) * NH + jt * 4;
                a0 += hl * wr0[0] + hh * wr1[0];
                a1 += hl * wr0[1] + hh * wr1[1];
                a2 += hl * wr0[2] + hh * wr1[2];
                a3 += hl * wr0[3] + hh * wr1[3];
            }
            h_l[t][jt * 2 + 0] = pk_bf16(silu_f(a0 * 0.125f), silu_f(a1 * 0.125f));
            h_l[t][jt * 2 + 1] = pk_bf16(silu_f(a2 * 0.125f), silu_f(a3 * 0.125f));
        }
    }
    __syncthreads();

    // ---------------- phase 2 ----------------
    const int wv = t >> 6, lane = t & 63;
    const int base = wv * 64;
    const int v_sd = snd_l[base + lane];   // sender of edge i in lane i

    // ---- pass A: slices 0 (p1) and 2 (p3); one se gather per edge --------
    {
        unsigned int WA[32], WC[32];
        #pragma unroll
        for (int q = 0; q < 32; q++) {
            WA[q] = pk_bf16(W4[(2 * q) * 320 + lane],       W4[(2 * q + 1) * 320 + lane]);
            WC[q] = pk_bf16(W4[(2 * q) * 320 + 128 + lane], W4[(2 * q + 1) * 320 + 128 + lane]);
        }
        float gc = s_st[(size_t)__builtin_amdgcn_readlane(v_sd, 0) * NC + lane];
        float gn = s_st[(size_t)__builtin_amdgcn_readlane(v_sd, 1) * NC + lane];
        int r_cur = -1;
        float acc1 = 0.f, acc3x = 0.f, acc3y = 0.f, acc3z = 0.f;
        #pragma unroll 2
        for (int ei = 0; ei < 64; ei++) {
            const int pn = (ei + 2 > 63) ? 63 : ei + 2;
            const float gf = s_st[(size_t)__builtin_amdgcn_readlane(v_sd, pn) * NC + lane];
            const int pos = base + ei;
            const int r = __builtin_amdgcn_readfirstlane(rcv_l[pos]);
            if (r != r_cur) {
                if (r_cur >= 0) {
                    float* mb = m + (size_t)r_cur * MPN;
                    unsafeAtomicAdd(mb + lane,             acc1);
                    unsafeAtomicAdd(mb + 128 + lane,       acc3x);
                    unsafeAtomicAdd(mb + 128 + 192 + lane, acc3y);
                    unsafeAtomicAdd(mb + 128 + 384 + lane, acc3z);
                    acc1 = acc3x = acc3y = acc3z = 0.f;
                }
                r_cur = r;
            }
            if (r >= 0) {
                const uint4* hp = (const uint4*)(&h_l[pos][0]);
                float da, db;
                dot2_bf16(hp, WA, WC, da, db);
                float w1w = da * 0.125f;   // 1/sqrt(64)
                float w3w = db * 0.125f;
                float se = gc;
                acc1 += w1w * se * sh0_l[pos];
                float t3 = w3w * se;
                acc3x += t3 * sh1_l[pos][0];
                acc3y += t3 * sh1_l[pos][1];
                acc3z += t3 * sh1_l[pos][2];
            }
            gc = gn; gn = gf;
        }
        if (r_cur >= 0) {
            float* mb = m + (size_t)r_cur * MPN;
            unsafeAtomicAdd(mb + lane,             acc1);
            unsafeAtomicAdd(mb + 128 + lane,       acc3x);
            unsafeAtomicAdd(mb + 128 + 192 + lane, acc3y);
            unsafeAtomicAdd(mb + 128 + 384 + lane, acc3z);
        }
    }

    // ---- pass B1: slices 1 (p2) and 3 (p4); one v gather per edge --------
    {
        unsigned int WB[32], WD[32];
        #pragma unroll
        for (int q = 0; q < 32; q++) {
            WB[q] = pk_bf16(W4[(2 * q) * 320 +  64 + lane], W4[(2 * q + 1) * 320 +  64 + lane]);
            WD[q] = pk_bf16(W4[(2 * q) * 320 + 192 + lane], W4[(2 * q + 1) * 320 + 192 + lane]);
        }
        float gxc, gyc, gzc, gxn, gyn, gzn;
        {
            size_t sb0 = (size_t)__builtin_amdgcn_readlane(v_sd, 0) * 192;
            size_t sb1 = (size_t)__builtin_amdgcn_readlane(v_sd, 1) * 192;
            gxc = v_st[sb0 + lane]; gyc = v_st[sb0 + 64 + lane]; gzc = v_st[sb0 + 128 + lane];
            gxn = v_st[sb1 + lane]; gyn = v_st[sb1 + 64 + lane]; gzn = v_st[sb1 + 128 + lane];
        }
        int r_cur = -1;
        float acc2 = 0.f, acc4x = 0.f, acc4y = 0.f, acc4z = 0.f;
        #pragma unroll 2
        for (int ei = 0; ei < 64; ei++) {
            const int pn = (ei + 2 > 63) ? 63 : ei + 2;
            size_t sb = (size_t)__builtin_amdgcn_readlane(v_sd, pn) * 192;
            const float gxf = v_st[sb + lane];
            const float gyf = v_st[sb + 64 + lane];
            const float gzf = v_st[sb + 128 + lane];
            const int pos = base + ei;
            const int r = __builtin_amdgcn_readfirstlane(rcv_l[pos]);
            if (r != r_cur) {
                if (r_cur >= 0) {
                    float* mb = m + (size_t)r_cur * MPN;
                    unsafeAtomicAdd(mb + 64 + lane,             acc2);
                    unsafeAtomicAdd(mb + 128 + 64 + lane,       acc4x);
                    unsafeAtomicAdd(mb + 128 + 192 + 64 + lane, acc4y);
                    unsafeAtomicAdd(mb + 128 + 384 + 64 + lane, acc4z);
                    acc2 = acc4x = acc4y = acc4z = 0.f;
                }
                r_cur = r;
            }
            if (r >= 0) {
                const uint4* hp = (const uint4*)(&h_l[pos][0]);
                float da, db;
                dot2_bf16(hp, WB, WD, da, db);
                float w2w = da * 0.125f;
                float w4w = db * 0.125f;
                float vx = gxc, vy = gyc, vz = gzc;
                float shx = sh1_l[pos][0], shy = sh1_l[pos][1], shz = sh1_l[pos][2];
                float dot = vx * shx + vy * shy + vz * shz;
                acc2 += w2w * dot * 0.5773502691896258f;   // 1/sqrt(3)
                float w4s = w4w * sh0_l[pos];
                acc4x += w4s * vx; acc4y += w4s * vy; acc4z += w4s * vz;
            }
            gxc = gxn; gyc = gyn; gzc = gzn;
            gxn = gxf; gyn = gyf; gzn = gzf;
        }
        if (r_cur >= 0) {
            float* mb = m + (size_t)r_cur * MPN;
            unsafeAtomicAdd(mb + 64 + lane,             acc2);
            unsafeAtomicAdd(mb + 128 + 64 + lane,       acc4x);
            unsafeAtomicAdd(mb + 128 + 192 + 64 + lane, acc4y);
            unsafeAtomicAdd(mb + 128 + 384 + 64 + lane, acc4z);
        }
    }

    // ---- pass B2: slice 4 (p5); one v gather per edge ---------------------
    {
        unsigned int WE[32];
        #pragma unroll
        for (int q = 0; q < 32; q++) {
            WE[q] = pk_bf16(W4[(2 * q) * 320 + 256 + lane], W4[(2 * q + 1) * 320 + 256 + lane]);
        }
        float gxc, gyc, gzc, gxn, gyn, gzn;
        {
            size_t sb0 = (size_t)__builtin_amdgcn_readlane(v_sd, 0) * 192;
            size_t sb1 = (size_t)__builtin_amdgcn_readlane(v_sd, 1) * 192;
            gxc = v_st[sb0 + lane]; gyc = v_st[sb0 + 64 + lane]; gzc = v_st[sb0 + 128 + lane];
            gxn = v_st[sb1 + lane]; gyn = v_st[sb1 + 64 + lane]; gzn = v_st[sb1 + 128 + lane];
        }
        int r_cur = -1;
        float acc5x = 0.f, acc5y = 0.f, acc5z = 0.f;
        #pragma unroll 2
        for (int ei = 0; ei < 64; ei++) {
            const int pn = (ei + 2 > 63) ? 63 : ei + 2;
            size_t sb = (size_t)__builtin_amdgcn_readlane(v_sd, pn) * 192;
            const float gxf = v_st[sb + lane];
            const float gyf = v_st[sb + 64 + lane];
            const float gzf = v_st[sb + 128 + lane];
            const int pos = base + ei;
            const int r = __builtin_amdgcn_readfirstlane(rcv_l[pos]);
            if (r != r_cur) {
                if (r_cur >= 0) {
                    float* mb = m + (size_t)r_cur * MPN;
                    unsafeAtomicAdd(mb + 128 + 128 + lane,       acc5x);
                    unsafeAtomicAdd(mb + 128 + 192 + 128 + lane, acc5y);
                    unsafeAtomicAdd(mb + 128 + 384 + 128 + lane, acc5z);
                    acc5x = acc5y = acc5z = 0.f;
                }
                r_cur = r;
            }
            if (r >= 0) {
                const uint4* hp = (const uint4*)(&h_l[pos][0]);
                float w5w = dot1_bf16(hp, WE) * 0.125f;
                float vx = gxc, vy = gyc, vz = gzc;
                float shx = sh1_l[pos][0], shy = sh1_l[pos][1], shz = sh1_l[pos][2];
                float w5s = w5w * 0.7071067811865476f;     // 1/sqrt(2)
                acc5x += w5s * (vy * shz - vz * shy);
                acc5y += w5s * (vz * shx - vx * shz);
                acc5z += w5s * (vx * shy - vy * shx);
            }
            gxc = gxn; gyc = gyn; gzc = gzn;
            gxn = gxf; gyn = gyf; gzn = gzf;
        }
        if (r_cur >= 0) {
            float* mb = m + (size_t)r_cur * MPN;
            unsafeAtomicAdd(mb + 128 + 128 + lane,       acc5x);
            unsafeAtomicAdd(mb + 128 + 192 + 128 + lane, acc5y);
            unsafeAtomicAdd(mb + 128 + 384 + 128 + lane, acc5z);
        }
    }
}

// ---------------------------------------------------------------------------
// Skip-connection as tiled GEMM: C[64n x 64d] per block, A[n][k]=feat*attr
// built on the fly (coalesced: lanes sweep k), B-tile staged, 4x4 register
// blocking. blockIdx.y = part (0: scalar->sc_s, 1..3: vector x -> sc_v).
// ---------------------------------------------------------------------------
__global__ __launch_bounds__(256)
void sc_kernel(const float* __restrict__ attrs, const float* __restrict__ fs,
               const float* __restrict__ fv,
               const float* __restrict__ Wss, const float* __restrict__ Wsv,
               float* __restrict__ out, int N)
{
    __shared__ float At[64][68];   // [kk][n]
    __shared__ float Bt[64][68];   // [kk][d]

    const int part = blockIdx.y;
    const int n0 = blockIdx.x * 64;
    const int t = threadIdx.x;
    const int tn = t & 15, td = t >> 4;
    const float* W = (part == 0) ? Wss : Wsv;
    const int x = part - 1;

    float acc[4][4];
    #pragma unroll
    for (int i = 0; i < 4; i++)
        #pragma unroll
        for (int j = 0; j < 4; j++) acc[i][j] = 0.f;

    for (int kt = 0; kt < 10; kt++) {
        __syncthreads();
        // build A-tile: lanes sweep kk (coalesced along k)
        for (int i = t; i < 4096; i += 256) {
            int n = i >> 6, kk = i & 63;
            int k = kt * 64 + kk;
            int c = k / 10, am = k - c * 10;
            int ng = n0 + n;
            float v = 0.f;
            if (ng < N) {
                float f = (part == 0) ? fs[(size_t)ng * 64 + c]
                                      : fv[((size_t)ng * 64 + c) * 3 + x];
                v = f * attrs[(size_t)ng * 10 + am];
            }
            At[kk][n] = v;
        }
        // load B-tile (coalesced in d)
        for (int i = t; i < 4096; i += 256) {
            int kk = i >> 6, d = i & 63;
            Bt[kk][d] = W[(size_t)(kt * 64 + kk) * 64 + d];
        }
        __syncthreads();
        #pragma unroll 8
        for (int kk = 0; kk < 64; kk++) {
            float a4[4], b4[4];
            #pragma unroll
            for (int i = 0; i < 4; i++) a4[i] = At[kk][tn * 4 + i];
            #pragma unroll
            for (int j = 0; j < 4; j++) b4[j] = Bt[kk][td * 4 + j];
            #pragma unroll
            for (int i = 0; i < 4; i++)
                #pragma unroll
                for (int j = 0; j < 4; j++) acc[i][j] += a4[i] * b4[j];
        }
    }

    const float inv_sc = 0.03952847075210474f;  // 1/sqrt(640)
    #pragma unroll
    for (int i = 0; i < 4; i++) {
        int ng = n0 + tn * 4 + i;
        if (ng >= N) continue;
        #pragma unroll
        for (int j = 0; j < 4; j++) {
            int d = td * 4 + j;
            float v = acc[i][j] * inv_sc;
            if (part == 0) out[(size_t)N * 256 + (size_t)ng * 64 + d] = v;
            else           out[(size_t)N * 320 + (size_t)ng * 192 + d * 3 + x] = v;
        }
    }
}

// ---------------------------------------------------------------------------
// Output linear as tiled GEMM over m. blockIdx.y = part (0: scalar k=128,
// 1..3: vector x, k=192). A-tile reads coalesced (lanes sweep kk).
// ---------------------------------------------------------------------------
__global__ __launch_bounds__(256)
void outlin_kernel(const float* __restrict__ m,
                   const float* __restrict__ Wos, const float* __restrict__ Wov,
                   float* __restrict__ out, int N)
{
    __shared__ float At[64][68];
    __shared__ float Bt[64][68];

    const int part = blockIdx.y;
    const int n0 = blockIdx.x * 64;
    const int t = threadIdx.x;
    const int tn = t & 15, td = t >> 4;
    const int x = part - 1;
    const int ntiles = (part == 0) ? 2 : 3;
    const int aoff = (part == 0) ? 0 : 128 + x * 192;
    const float* W = (part == 0) ? Wos : Wov;

    float acc[4][4];
    #pragma unroll
    for (int i = 0; i < 4; i++)
        #pragma unroll
        for (int j = 0; j < 4; j++) acc[i][j] = 0.f;

    for (int kt = 0; kt < ntiles; kt++) {
        __syncthreads();
        for (int i = t; i < 4096; i += 256) {
            int n = i >> 6, kk = i & 63;
            int ng = n0 + n;
            At[kk][n] = (ng < N) ? m[(size_t)ng * MPN + aoff + kt * 64 + kk] : 0.f;
        }
        for (int i = t; i < 4096; i += 256) {
            int kk = i >> 6, d = i & 63;
            Bt[kk][d] = W[(size_t)(kt * 64 + kk) * 64 + d];
        }
        __syncthreads();
        #pragma unroll 8
        for (int kk = 0; kk < 64; kk++) {
            float a4[4], b4[4];
            #pragma unroll
            for (int i = 0; i < 4; i++) a4[i] = At[kk][tn * 4 + i];
            #pragma unroll
            for (int j = 0; j < 4; j++) b4[j] = Bt[kk][td * 4 + j];
            #pragma unroll
            for (int i = 0; i < 4; i++)
                #pragma unroll
                for (int j = 0; j < 4; j++) acc[i][j] += a4[i] * b4[j];
        }
    }

    const float scale = (part == 0) ? 0.005524271728019903f    // 1/(sqrt(128)*16)
                                    : 0.004510527174164819f;   // 1/(sqrt(192)*16)
    #pragma unroll
    for (int i = 0; i < 4; i++) {
        int ng = n0 + tn * 4 + i;
        if (ng >= N) continue;
        #pragma unroll
        for (int j = 0; j < 4; j++) {
            int d = td * 4 + j;
            float v = acc[i][j] * scale;
            if (part == 0) out[(size_t)ng * 64 + d] = v;
            else           out[(size_t)N * 64 + (size_t)ng * 192 + d * 3 + x] = v;
        }
    }
}

// ---------------------------------------------------------------------------
extern "C" void kernel_launch(void* const* d_in, const int* in_sizes, int n_in,
                              void* d_out, int out_size, void* d_ws, size_t ws_size,
                              hipStream_t stream)
{
    const float* attrs = (const float*)d_in[0];
    const float* fs    = (const float*)d_in[1];
    const float* fv    = (const float*)d_in[2];
    const float* sh0   = (const float*)d_in[3];
    const float* sh1   = (const float*)d_in[4];
    const float* ef    = (const float*)d_in[5];
    const int*   snd   = (const int*)d_in[6];
    const int*   rcv   = (const int*)d_in[7];
    const float* Wss   = (const float*)d_in[8];
    const float* Wsv   = (const float*)d_in[9];
    const float* Wes   = (const float*)d_in[10];
    const float* Wev   = (const float*)d_in[11];
    const float* W1    = (const float*)d_in[12];
    const float* W2    = (const float*)d_in[13];
    const float* W3    = (const float*)d_in[14];
    const float* W4    = (const float*)d_in[15];
    const float* Wos   = (const float*)d_in[16];
    const float* Wov   = (const float*)d_in[17];

    const int N = in_sizes[0] / NATTR;   // 50000
    const int E = in_sizes[6];           // 320000

    float* out = (float*)d_out;
    const float* s_st = out + (size_t)N * 256;  // self-linear s scratch
    const float* v_st = out + (size_t)N * 320;  // self-linear v scratch

    // CSR int scratch in d_out's out region (overwritten later by outlin)
    int* deg     = (int*)d_out;
    int* cursor  = deg + N;
    int* row_ptr = cursor + N;
    int* eidx    = row_ptr + N + 1;

    float* m = (float*)d_ws;             // N*704 f32 = 140.8 MB (fits: round-4)

    hipMemsetAsync(deg, 0, (size_t)2 * N * sizeof(int), stream);
    hipMemsetAsync(m, 0, (size_t)N * MPN * sizeof(float), stream);

    const int eb = (E + 255) / 256;
    hist_kernel<<<eb, 256, 0, stream>>>(rcv, deg, E);
    scan_kernel<<<1, 256, 0, stream>>>(deg, row_ptr, N);
    fill_kernel<<<eb, 256, 0, stream>>>(rcv, row_ptr, cursor, eidx, E);

    self_kernel<<<(N + 3) / 4, 256, 0, stream>>>(fs, fv, Wes, Wev, out, N);

    const int nbe = (E + TEB - 1) / TEB;
    edge_kernel<<<nbe, 128, 0, stream>>>(ef, sh0, sh1, snd, rcv,
                                         W1, W2, W3, W4, s_st, v_st,
                                         eidx, m, E);

    dim3 g_out((N + 63) / 64, 4);
    outlin_kernel<<<g_out, 256, 0, stream>>>(m, Wos, Wov, out, N);

    dim3 g_sc((N + 63) / 64, 4);
    sc_kernel<<<g_sc, 256, 0, stream>>>(attrs, fs, fv, Wss, Wsv, out, N);
}

// Round 6
// 1212.616 us; speedup vs baseline: 2.3021x; 1.5013x over previous
//
#include <hip/hip_runtime.h>

#define NC    64      // channels C
#define NATTR 10      // node attrs
#define NH    64      // radial MLP hidden
#define NRAD  8       // radial features
#define TEB   128     // CSR positions per edge block
#define MPN   704     // f32 message floats per node

__device__ __forceinline__ float silu_f(float x) { return x / (1.0f + __expf(-x)); }

// ---------------- f16x2 pack helpers + hardware dot2 ----------------------
// NOTE: on this clang, __builtin_amdgcn_cvt_pkrtz / fdot2 use the __fp16
// ext-vector type (NOT _Float16) -- r5 failed to compile on that mismatch.
typedef __fp16 h2v __attribute__((ext_vector_type(2)));

__device__ __forceinline__ unsigned int pkh(float lo, float hi)
{
    union { h2v h; unsigned int u; } cv;
    cv.h = __builtin_amdgcn_cvt_pkrtz(lo, hi);   // v_cvt_pkrtz_f16_f32
    return cv.u;
}
__device__ __forceinline__ h2v uph(unsigned int u)
{
    union { unsigned int u; h2v h; } cv;
    cv.u = u;
    return cv.h;
}

#if defined(__has_builtin)
#if __has_builtin(__builtin_amdgcn_fdot2)
#define HAS_FDOT2 1
#endif
#endif

__device__ __forceinline__ float fd2(unsigned int a, unsigned int b, float c)
{
#ifdef HAS_FDOT2
    return __builtin_amdgcn_fdot2(uph(a), uph(b), c, false);  // v_dot2_f32_f16
#else
    h2v x = uph(a), y = uph(b);
    return c + (float)x[0] * (float)y[0] + (float)x[1] * (float)y[1];
#endif
}

// ---------------------------------------------------------------------------
// d_out layout (f32, out_size = N*512):
//   out_s : [0,      N*64 )   -- also CSR int scratch until out written
//   out_v : [N*64,   N*256)
//   sc_s  : [N*256,  N*320)   -- self-linear s scratch until sc_kernel
//   sc_v  : [N*320,  N*512)   -- self-linear v scratch until sc_kernel
// ws: m[N*704] f32 message accumulator (140.8 MB)
// ---------------------------------------------------------------------------

// ---------------- CSR build (scratch ints live in d_out's out region) ------
__global__ void hist_kernel(const int* __restrict__ rcv, int* __restrict__ deg, int E)
{
    int e = blockIdx.x * 256 + threadIdx.x;
    if (e < E) atomicAdd(&deg[rcv[e]], 1);
}

__global__ __launch_bounds__(256)
void scan_kernel(const int* __restrict__ deg, int* __restrict__ row_ptr, int N)
{
    __shared__ int sums[256];
    __shared__ int offs[257];
    const int t = threadIdx.x;
    const int chunk = (N + 255) / 256;
    int b = t * chunk, e = min(N, b + chunk);
    int s = 0;
    for (int k = b; k < e; k++) s += deg[k];
    sums[t] = s;
    __syncthreads();
    if (t == 0) {
        int run = 0;
        for (int i = 0; i < 256; i++) { offs[i] = run; run += sums[i]; }
        offs[256] = run;
    }
    __syncthreads();
    int run = offs[t];
    for (int k = b; k < e; k++) { row_ptr[k] = run; run += deg[k]; }
    if (t == 255) row_ptr[N] = offs[256];
}

__global__ void fill_kernel(const int* __restrict__ rcv, const int* __restrict__ row_ptr,
                            int* __restrict__ cursor, int* __restrict__ eidx, int E)
{
    int e = blockIdx.x * 256 + threadIdx.x;
    if (e < E) {
        int r = rcv[e];
        int pos = atomicAdd(&cursor[r], 1);
        eidx[row_ptr[r] + pos] = e;
    }
}

// ---------------- self linear: wave-per-node, 4 nodes/block ----------------
__global__ __launch_bounds__(256)
void self_kernel(const float* __restrict__ fs, const float* __restrict__ fv,
                 const float* __restrict__ Wes, const float* __restrict__ Wev,
                 float* __restrict__ out, int N)
{
    __shared__ float s_l[4][NC];
    __shared__ float v_l[4][3][NC];
    const int t = threadIdx.x, wv = t >> 6, lane = t & 63;
    const int n = blockIdx.x * 4 + wv;

    if (n < N) {
        s_l[wv][lane] = fs[(size_t)n * NC + lane];
        v_l[wv][0][lane] = fv[(size_t)n * NC * 3 + lane * 3 + 0];
        v_l[wv][1][lane] = fv[(size_t)n * NC * 3 + lane * 3 + 1];
        v_l[wv][2][lane] = fv[(size_t)n * NC * 3 + lane * 3 + 2];
    }
    __syncthreads();
    if (n >= N) return;

    const int d = lane;
    float a = 0.f, bx = 0.f, by = 0.f, bz = 0.f;
    #pragma unroll 8
    for (int c = 0; c < NC; c++) {
        float ws = Wes[c * NC + d];
        float wvv = Wev[c * NC + d];
        a  += s_l[wv][c] * ws;
        bx += v_l[wv][0][c] * wvv;
        by += v_l[wv][1][c] * wvv;
        bz += v_l[wv][2][c] * wvv;
    }
    out[(size_t)N * 256 + (size_t)n * NC + d]            = a  * 0.125f;
    out[(size_t)N * 320 + (size_t)n * 192 +       d]     = bx * 0.125f;
    out[(size_t)N * 320 + (size_t)n * 192 +  64 + d]     = by * 0.125f;
    out[(size_t)N * 320 + (size_t)n * 192 + 128 + d]     = bz * 0.125f;
}

// ---------------------------------------------------------------------------
// Edge kernel: 128 CSR positions per 128-thread block.
// Phase 1: thread-per-edge radial MLP; h1 f32 regs -> h2 packed f16 in 32
//   uint regs -> h3 packed f16x2 -> LDS (21.5 KB total -> 7 blocks/CU).
// Phase 2: wave-per-edge layer 4 + tensor product, FIVE single-slice passes
//   (32 W-uints each -- guaranteed register-resident; r4 showed 64+ uint
//   sets get rematerialized as per-iteration loads). Each dot = 32 x
//   v_dot2_f32_f16 (no unpack VALU). Receivers preloaded to lane regs and
//   broadcast via readlane (no per-iteration LDS on the flush path).
//   Named double-buffer prefetch depth 2; CSR receiver-run register
//   accumulation flushes atomics only on receiver change.
// m per-node layout: [0,64) p1 | [64,128) p2 | 128 + x*192 + {0:p3,64:p4,128:p5}
// ---------------------------------------------------------------------------
__global__ __launch_bounds__(128, 3)
void edge_kernel(const float* __restrict__ ef, const float* __restrict__ sh0,
                 const float* __restrict__ sh1,
                 const int* __restrict__ snd, const int* __restrict__ rcv,
                 const float* __restrict__ W1, const float* __restrict__ W2,
                 const float* __restrict__ W3, const float* __restrict__ W4,
                 const float* __restrict__ s_st, const float* __restrict__ v_st,
                 const int* __restrict__ eidx,
                 float* __restrict__ m, int E)
{
    __shared__ unsigned int h_l[TEB][36];   // 32 packed f16x2 + pad (144B rows)
    __shared__ float sh1_l[TEB][3];
    __shared__ float sh0_l[TEB];
    __shared__ int   snd_l[TEB];
    __shared__ int   rcv_l[TEB];

    const int t = threadIdx.x;
    const int p0 = blockIdx.x * TEB;

    // ---------------- phase 1 ----------------
    {
        int p = p0 + t;
        bool valid = p < E;
        int e = valid ? eidx[p] : 0;
        snd_l[t] = valid ? snd[e] : 0;
        rcv_l[t] = valid ? rcv[e] : -1;
        sh0_l[t] = valid ? sh0[e] : 0.f;
        sh1_l[t][0] = valid ? sh1[(size_t)e * 3 + 0] : 0.f;
        sh1_l[t][1] = valid ? sh1[(size_t)e * 3 + 1] : 0.f;
        sh1_l[t][2] = valid ? sh1[(size_t)e * 3 + 2] : 0.f;

        float x[NRAD];
        #pragma unroll
        for (int r = 0; r < NRAD; r++)
            x[r] = valid ? ef[(size_t)e * NRAD + r] : 0.f;

        // layer 1: 8 -> 64 (h1 in registers)
        float h1[NH];
        #pragma unroll
        for (int j = 0; j < NH; j++) {
            float a = 0.f;
            #pragma unroll
            for (int r = 0; r < NRAD; r++) a += x[r] * W1[r * NH + j];
            h1[j] = silu_f(a * 0.35355339059327373f);   // 1/sqrt(8)
        }

        // layer 2: h1(f32 regs) -> h2 packed f16 (32 uint regs)
        unsigned int h2p[32];
        for (int jt = 0; jt < 16; jt++) {
            float a0 = 0.f, a1 = 0.f, a2 = 0.f, a3 = 0.f;
            #pragma unroll
            for (int c = 0; c < NH; c++) {
                float hv = h1[c];
                const float* wr = W2 + c * NH + jt * 4;
                a0 += hv * wr[0]; a1 += hv * wr[1];
                a2 += hv * wr[2]; a3 += hv * wr[3];
            }
            h2p[jt * 2 + 0] = pkh(silu_f(a0 * 0.125f), silu_f(a1 * 0.125f));
            h2p[jt * 2 + 1] = pkh(silu_f(a2 * 0.125f), silu_f(a3 * 0.125f));
        }
        // layer 3: h2 packed -> h3 packed -> LDS (h1 dead; regs reused)
        for (int jt = 0; jt < 16; jt++) {
            float a0 = 0.f, a1 = 0.f, a2 = 0.f, a3 = 0.f;
            #pragma unroll
            for (int cp = 0; cp < 32; cp++) {
                h2v u = uph(h2p[cp]);
                float hl = (float)u[0], hh = (float)u[1];
                const float* wr0 = W3 + (2 * cp) * NH + jt * 4;
                const float* wr1 = W3 + (2 * cp + 1) * NH + jt * 4;
                a0 += hl * wr0[0] + hh * wr1[0];
                a1 += hl * wr0[1] + hh * wr1[1];
                a2 += hl * wr0[2] + hh * wr1[2];
                a3 += hl * wr0[3] + hh * wr1[3];
            }
            h_l[t][jt * 2 + 0] = pkh(silu_f(a0 * 0.125f), silu_f(a1 * 0.125f));
            h_l[t][jt * 2 + 1] = pkh(silu_f(a2 * 0.125f), silu_f(a3 * 0.125f));
        }
    }
    __syncthreads();

    // ---------------- phase 2 ----------------
    const int wv = t >> 6, lane = t & 63;
    const int base = wv * 64;
    const int v_sd = snd_l[base + lane];   // sender of edge i in lane i
    const int v_rc = rcv_l[base + lane];   // receiver of edge i in lane i

// 32 x v_dot2_f32_f16 against one register W-column slice
#define DOT32(W, res)                                                     \
    {                                                                     \
        const uint4* hp_ = (const uint4*)(&h_l[pos][0]);                  \
        float w_ = 0.f;                                                   \
        _Pragma("unroll")                                                 \
        for (int q8 = 0; q8 < 8; q8++) {                                  \
            uint4 hu = hp_[q8];                                           \
            w_ = fd2(hu.x, W[q8 * 4 + 0], w_);                            \
            w_ = fd2(hu.y, W[q8 * 4 + 1], w_);                            \
            w_ = fd2(hu.z, W[q8 * 4 + 2], w_);                            \
            w_ = fd2(hu.w, W[q8 * 4 + 3], w_);                            \
        }                                                                 \
        res = w_ * 0.125f; /* 1/sqrt(64) */                               \
    }

    // ---- slice 0: p1 (se gather) ------------------------------------------
    {
        unsigned int W0[32];
        #pragma unroll
        for (int q = 0; q < 32; q++)
            W0[q] = pkh(W4[(2 * q) * 320 + lane], W4[(2 * q + 1) * 320 + lane]);
        float gc = s_st[(size_t)__builtin_amdgcn_readlane(v_sd, 0) * NC + lane];
        float gn = s_st[(size_t)__builtin_amdgcn_readlane(v_sd, 1) * NC + lane];
        int r_cur = -1;
        float acc = 0.f;
        #pragma unroll 2
        for (int ei = 0; ei < 64; ei++) {
            const int pn = (ei + 2 > 63) ? 63 : ei + 2;
            const float gf = s_st[(size_t)__builtin_amdgcn_readlane(v_sd, pn) * NC + lane];
            const int r = __builtin_amdgcn_readlane(v_rc, ei);
            if (r != r_cur) {
                if (r_cur >= 0) {
                    unsafeAtomicAdd(m + (size_t)r_cur * MPN + lane, acc);
                    acc = 0.f;
                }
                r_cur = r;
            }
            if (r >= 0) {
                const int pos = base + ei;
                float w;
                DOT32(W0, w);
                acc += w * gc * sh0_l[pos];
            }
            gc = gn; gn = gf;
        }
        if (r_cur >= 0) unsafeAtomicAdd(m + (size_t)r_cur * MPN + lane, acc);
    }

    // ---- slice 2: p3 (se gather) ------------------------------------------
    {
        unsigned int W0[32];
        #pragma unroll
        for (int q = 0; q < 32; q++)
            W0[q] = pkh(W4[(2 * q) * 320 + 128 + lane], W4[(2 * q + 1) * 320 + 128 + lane]);
        float gc = s_st[(size_t)__builtin_amdgcn_readlane(v_sd, 0) * NC + lane];
        float gn = s_st[(size_t)__builtin_amdgcn_readlane(v_sd, 1) * NC + lane];
        int r_cur = -1;
        float ax = 0.f, ay = 0.f, az = 0.f;
        #pragma unroll 2
        for (int ei = 0; ei < 64; ei++) {
            const int pn = (ei + 2 > 63) ? 63 : ei + 2;
            const float gf = s_st[(size_t)__builtin_amdgcn_readlane(v_sd, pn) * NC + lane];
            const int r = __builtin_amdgcn_readlane(v_rc, ei);
            if (r != r_cur) {
                if (r_cur >= 0) {
                    float* mb = m + (size_t)r_cur * MPN + 128;
                    unsafeAtomicAdd(mb + lane,       ax);
                    unsafeAtomicAdd(mb + 192 + lane, ay);
                    unsafeAtomicAdd(mb + 384 + lane, az);
                    ax = ay = az = 0.f;
                }
                r_cur = r;
            }
            if (r >= 0) {
                const int pos = base + ei;
                float w;
                DOT32(W0, w);
                float t3 = w * gc;
                ax += t3 * sh1_l[pos][0];
                ay += t3 * sh1_l[pos][1];
                az += t3 * sh1_l[pos][2];
            }
            gc = gn; gn = gf;
        }
        if (r_cur >= 0) {
            float* mb = m + (size_t)r_cur * MPN + 128;
            unsafeAtomicAdd(mb + lane,       ax);
            unsafeAtomicAdd(mb + 192 + lane, ay);
            unsafeAtomicAdd(mb + 384 + lane, az);
        }
    }

    // ---- slice 1: p2 (v gather) -------------------------------------------
    {
        unsigned int W0[32];
        #pragma unroll
        for (int q = 0; q < 32; q++)
            W0[q] = pkh(W4[(2 * q) * 320 + 64 + lane], W4[(2 * q + 1) * 320 + 64 + lane]);
        float gxc, gyc, gzc, gxn, gyn, gzn;
        {
            size_t sb0 = (size_t)__builtin_amdgcn_readlane(v_sd, 0) * 192;
            size_t sb1 = (size_t)__builtin_amdgcn_readlane(v_sd, 1) * 192;
            gxc = v_st[sb0 + lane]; gyc = v_st[sb0 + 64 + lane]; gzc = v_st[sb0 + 128 + lane];
            gxn = v_st[sb1 + lane]; gyn = v_st[sb1 + 64 + lane]; gzn = v_st[sb1 + 128 + lane];
        }
        int r_cur = -1;
        float acc = 0.f;
        #pragma unroll 2
        for (int ei = 0; ei < 64; ei++) {
            const int pn = (ei + 2 > 63) ? 63 : ei + 2;
            size_t sb = (size_t)__builtin_amdgcn_readlane(v_sd, pn) * 192;
            const float gxf = v_st[sb + lane];
            const float gyf = v_st[sb + 64 + lane];
            const float gzf = v_st[sb + 128 + lane];
            const int r = __builtin_amdgcn_readlane(v_rc, ei);
            if (r != r_cur) {
                if (r_cur >= 0) {
                    unsafeAtomicAdd(m + (size_t)r_cur * MPN + 64 + lane, acc);
                    acc = 0.f;
                }
                r_cur = r;
            }
            if (r >= 0) {
                const int pos = base + ei;
                float w;
                DOT32(W0, w);
                float dot = gxc * sh1_l[pos][0] + gyc * sh1_l[pos][1] + gzc * sh1_l[pos][2];
                acc += w * dot * 0.5773502691896258f;   // 1/sqrt(3)
            }
            gxc = gxn; gyc = gyn; gzc = gzn;
            gxn = gxf; gyn = gyf; gzn = gzf;
        }
        if (r_cur >= 0) unsafeAtomicAdd(m + (size_t)r_cur * MPN + 64 + lane, acc);
    }

    // ---- slice 3: p4 (v gather) -------------------------------------------
    {
        unsigned int W0[32];
        #pragma unroll
        for (int q = 0; q < 32; q++)
            W0[q] = pkh(W4[(2 * q) * 320 + 192 + lane], W4[(2 * q + 1) * 320 + 192 + lane]);
        float gxc, gyc, gzc, gxn, gyn, gzn;
        {
            size_t sb0 = (size_t)__builtin_amdgcn_readlane(v_sd, 0) * 192;
            size_t sb1 = (size_t)__builtin_amdgcn_readlane(v_sd, 1) * 192;
            gxc = v_st[sb0 + lane]; gyc = v_st[sb0 + 64 + lane]; gzc = v_st[sb0 + 128 + lane];
            gxn = v_st[sb1 + lane]; gyn = v_st[sb1 + 64 + lane]; gzn = v_st[sb1 + 128 + lane];
        }
        int r_cur = -1;
        float ax = 0.f, ay = 0.f, az = 0.f;
        #pragma unroll 2
        for (int ei = 0; ei < 64; ei++) {
            const int pn = (ei + 2 > 63) ? 63 : ei + 2;
            size_t sb = (size_t)__builtin_amdgcn_readlane(v_sd, pn) * 192;
            const float gxf = v_st[sb + lane];
            const float gyf = v_st[sb + 64 + lane];
            const float gzf = v_st[sb + 128 + lane];
            const int r = __builtin_amdgcn_readlane(v_rc, ei);
            if (r != r_cur) {
                if (r_cur >= 0) {
                    float* mb = m + (size_t)r_cur * MPN + 128 + 64;
                    unsafeAtomicAdd(mb + lane,       ax);
                    unsafeAtomicAdd(mb + 192 + lane, ay);
                    unsafeAtomicAdd(mb + 384 + lane, az);
                    ax = ay = az = 0.f;
                }
                r_cur = r;
            }
            if (r >= 0) {
                const int pos = base + ei;
                float w;
                DOT32(W0, w);
                float w4s = w * sh0_l[pos];
                ax += w4s * gxc; ay += w4s * gyc; az += w4s * gzc;
            }
            gxc = gxn; gyc = gyn; gzc = gzn;
            gxn = gxf; gyn = gyf; gzn = gzf;
        }
        if (r_cur >= 0) {
            float* mb = m + (size_t)r_cur * MPN + 128 + 64;
            unsafeAtomicAdd(mb + lane,       ax);
            unsafeAtomicAdd(mb + 192 + lane, ay);
            unsafeAtomicAdd(mb + 384 + lane, az);
        }
    }

    // ---- slice 4: p5 (v gather) -------------------------------------------
    {
        unsigned int W0[32];
        #pragma unroll
        for (int q = 0; q < 32; q++)
            W0[q] = pkh(W4[(2 * q) * 320 + 256 + lane], W4[(2 * q + 1) * 320 + 256 + lane]);
        float gxc, gyc, gzc, gxn, gyn, gzn;
        {
            size_t sb0 = (size_t)__builtin_amdgcn_readlane(v_sd, 0) * 192;
            size_t sb1 = (size_t)__builtin_amdgcn_readlane(v_sd, 1) * 192;
            gxc = v_st[sb0 + lane]; gyc = v_st[sb0 + 64 + lane]; gzc = v_st[sb0 + 128 + lane];
            gxn = v_st[sb1 + lane]; gyn = v_st[sb1 + 64 + lane]; gzn = v_st[sb1 + 128 + lane];
        }
        int r_cur = -1;
        float ax = 0.f, ay = 0.f, az = 0.f;
        #pragma unroll 2
        for (int ei = 0; ei < 64; ei++) {
            const int pn = (ei + 2 > 63) ? 63 : ei + 2;
            size_t sb = (size_t)__builtin_amdgcn_readlane(v_sd, pn) * 192;
            const float gxf = v_st[sb + lane];
            const float gyf = v_st[sb + 64 + lane];
            const float gzf = v_st[sb + 128 + lane];
            const int r = __builtin_amdgcn_readlane(v_rc, ei);
            if (r != r_cur) {
                if (r_cur >= 0) {
                    float* mb = m + (size_t)r_cur * MPN + 128 + 128;
                    unsafeAtomicAdd(mb + lane,       ax);
                    unsafeAtomicAdd(mb + 192 + lane, ay);
                    unsafeAtomicAdd(mb + 384 + lane, az);
                    ax = ay = az = 0.f;
                }
                r_cur = r;
            }
            if (r >= 0) {
                const int pos = base + ei;
                float w;
                DOT32(W0, w);
                float shx = sh1_l[pos][0], shy = sh1_l[pos][1], shz = sh1_l[pos][2];
                float w5s = w * 0.7071067811865476f;     // 1/sqrt(2)
                ax += w5s * (gyc * shz - gzc * shy);
                ay += w5s * (gzc * shx - gxc * shz);
                az += w5s * (gxc * shy - gyc * shx);
            }
            gxc = gxn; gyc = gyn; gzc = gzn;
            gxn = gxf; gyn = gyf; gzn = gzf;
        }
        if (r_cur >= 0) {
            float* mb = m + (size_t)r_cur * MPN + 128 + 128;
            unsafeAtomicAdd(mb + lane,       ax);
            unsafeAtomicAdd(mb + 192 + lane, ay);
            unsafeAtomicAdd(mb + 384 + lane, az);
        }
    }
#undef DOT32
}

// ---------------------------------------------------------------------------
// Skip-connection as tiled GEMM with f16x2-packed LDS tiles + v_dot2_f32_f16.
// C[64n x 64d] per block, A[n][k]=feat*attr built on the fly, 4x4 register
// blocking, f32 accumulation. LDS 17.4 KB (was 34.8) -> 2x occupancy.
// blockIdx.y = part (0: scalar->sc_s, 1..3: vector x -> sc_v).
// ---------------------------------------------------------------------------
__global__ __launch_bounds__(256)
void sc_kernel(const float* __restrict__ attrs, const float* __restrict__ fs,
               const float* __restrict__ fv,
               const float* __restrict__ Wss, const float* __restrict__ Wsv,
               float* __restrict__ out, int N)
{
    __shared__ unsigned int At[32][68];   // [k-pair][n] f16x2 (272B rows, 16B-mult)
    __shared__ unsigned int Bt[32][68];   // [k-pair][d] f16x2

    const int part = blockIdx.y;
    const int n0 = blockIdx.x * 64;
    const int t = threadIdx.x;
    const int tn = t & 15, td = t >> 4;
    const float* W = (part == 0) ? Wss : Wsv;
    const int x = part - 1;

    float acc[4][4];
    #pragma unroll
    for (int i = 0; i < 4; i++)
        #pragma unroll
        for (int j = 0; j < 4; j++) acc[i][j] = 0.f;

    for (int kt = 0; kt < 10; kt++) {
        __syncthreads();
        // build A-tile (packed k-pairs)
        for (int i = t; i < 2048; i += 256) {
            int n = i >> 5, kp = i & 31;
            int k0 = kt * 64 + kp * 2;
            int c0 = k0 / 10, a0 = k0 - c0 * 10;
            int k1 = k0 + 1;
            int c1 = k1 / 10, a1 = k1 - c1 * 10;
            int ng = n0 + n;
            float f0 = 0.f, f1 = 0.f;
            if (ng < N) {
                float fa = (part == 0) ? fs[(size_t)ng * 64 + c0]
                                       : fv[((size_t)ng * 64 + c0) * 3 + x];
                float fb = (part == 0) ? fs[(size_t)ng * 64 + c1]
                                       : fv[((size_t)ng * 64 + c1) * 3 + x];
                f0 = fa * attrs[(size_t)ng * 10 + a0];
                f1 = fb * attrs[(size_t)ng * 10 + a1];
            }
            At[kp][n] = pkh(f0, f1);
        }
        // load B-tile (packed k-pairs, coalesced in d)
        for (int i = t; i < 2048; i += 256) {
            int kp = i >> 6, d = i & 63;
            Bt[kp][d] = pkh(W[(size_t)(kt * 64 + 2 * kp) * 64 + d],
                            W[(size_t)(kt * 64 + 2 * kp + 1) * 64 + d]);
        }
        __syncthreads();
        #pragma unroll 8
        for (int kp = 0; kp < 32; kp++) {
            uint4 au = *(const uint4*)(&At[kp][tn * 4]);
            uint4 bu = *(const uint4*)(&Bt[kp][td * 4]);
            unsigned int aa[4] = {au.x, au.y, au.z, au.w};
            unsigned int bb[4] = {bu.x, bu.y, bu.z, bu.w};
            #pragma unroll
            for (int i = 0; i < 4; i++)
                #pragma unroll
                for (int j = 0; j < 4; j++)
                    acc[i][j] = fd2(aa[i], bb[j], acc[i][j]);
        }
    }

    const float inv_sc = 0.03952847075210474f;  // 1/sqrt(640)
    #pragma unroll
    for (int i = 0; i < 4; i++) {
        int ng = n0 + tn * 4 + i;
        if (ng >= N) continue;
        #pragma unroll
        for (int j = 0; j < 4; j++) {
            int d = td * 4 + j;
            float v = acc[i][j] * inv_sc;
            if (part == 0) out[(size_t)N * 256 + (size_t)ng * 64 + d] = v;
            else           out[(size_t)N * 320 + (size_t)ng * 192 + d * 3 + x] = v;
        }
    }
}

// ---------------------------------------------------------------------------
// Output linear as tiled GEMM over m, f16x2-packed + v_dot2_f32_f16.
// blockIdx.y = part (0: scalar k=128, 1..3: vector x, k=192).
// ---------------------------------------------------------------------------
__global__ __launch_bounds__(256)
void outlin_kernel(const float* __restrict__ m,
                   const float* __restrict__ Wos, const float* __restrict__ Wov,
                   float* __restrict__ out, int N)
{
    __shared__ unsigned int At[32][68];
    __shared__ unsigned int Bt[32][68];

    const int part = blockIdx.y;
    const int n0 = blockIdx.x * 64;
    const int t = threadIdx.x;
    const int tn = t & 15, td = t >> 4;
    const int x = part - 1;
    const int ntiles = (part == 0) ? 2 : 3;
    const int aoff = (part == 0) ? 0 : 128 + x * 192;
    const float* W = (part == 0) ? Wos : Wov;

    float acc[4][4];
    #pragma unroll
    for (int i = 0; i < 4; i++)
        #pragma unroll
        for (int j = 0; j < 4; j++) acc[i][j] = 0.f;

    for (int kt = 0; kt < ntiles; kt++) {
        __syncthreads();
        for (int i = t; i < 2048; i += 256) {
            int n = i >> 5, kp = i & 31;
            int ng = n0 + n;
            float f0 = 0.f, f1 = 0.f;
            if (ng < N) {
                const float* mp = m + (size_t)ng * MPN + aoff + kt * 64 + kp * 2;
                f0 = mp[0]; f1 = mp[1];
            }
            At[kp][n] = pkh(f0, f1);
        }
        for (int i = t; i < 2048; i += 256) {
            int kp = i >> 6, d = i & 63;
            Bt[kp][d] = pkh(W[(size_t)(kt * 64 + 2 * kp) * 64 + d],
                            W[(size_t)(kt * 64 + 2 * kp + 1) * 64 + d]);
        }
        __syncthreads();
        #pragma unroll 8
        for (int kp = 0; kp < 32; kp++) {
            uint4 au = *(const uint4*)(&At[kp][tn * 4]);
            uint4 bu = *(const uint4*)(&Bt[kp][td * 4]);
            unsigned int aa[4] = {au.x, au.y, au.z, au.w};
            unsigned int bb[4] = {bu.x, bu.y, bu.z, bu.w};
            #pragma unroll
            for (int i = 0; i < 4; i++)
                #pragma unroll
                for (int j = 0; j < 4; j++)
                    acc[i][j] = fd2(aa[i], bb[j], acc[i][j]);
        }
    }

    const float scale = (part == 0) ? 0.005524271728019903f    // 1/(sqrt(128)*16)
                                    : 0.004510527174164819f;   // 1/(sqrt(192)*16)
    #pragma unroll
    for (int i = 0; i < 4; i++) {
        int ng = n0 + tn * 4 + i;
        if (ng >= N) continue;
        #pragma unroll
        for (int j = 0; j < 4; j++) {
            int d = td * 4 + j;
            float v = acc[i][j] * scale;
            if (part == 0) out[(size_t)ng * 64 + d] = v;
            else           out[(size_t)N * 64 + (size_t)ng * 192 + d * 3 + x] = v;
        }
    }
}

// ---------------------------------------------------------------------------
extern "C" void kernel_launch(void* const* d_in, const int* in_sizes, int n_in,
                              void* d_out, int out_size, void* d_ws, size_t ws_size,
                              hipStream_t stream)
{
    const float* attrs = (const float*)d_in[0];
    const float* fs    = (const float*)d_in[1];
    const float* fv    = (const float*)d_in[2];
    const float* sh0   = (const float*)d_in[3];
    const float* sh1   = (const float*)d_in[4];
    const float* ef    = (const float*)d_in[5];
    const int*   snd   = (const int*)d_in[6];
    const int*   rcv   = (const int*)d_in[7];
    const float* Wss   = (const float*)d_in[8];
    const float* Wsv   = (const float*)d_in[9];
    const float* Wes   = (const float*)d_in[10];
    const float* Wev   = (const float*)d_in[11];
    const float* W1    = (const float*)d_in[12];
    const float* W2    = (const float*)d_in[13];
    const float* W3    = (const float*)d_in[14];
    const float* W4    = (const float*)d_in[15];
    const float* Wos   = (const float*)d_in[16];
    const float* Wov   = (const float*)d_in[17];

    const int N = in_sizes[0] / NATTR;   // 50000
    const int E = in_sizes[6];           // 320000

    float* out = (float*)d_out;
    const float* s_st = out + (size_t)N * 256;  // self-linear s scratch
    const float* v_st = out + (size_t)N * 320;  // self-linear v scratch

    // CSR int scratch in d_out's out region (overwritten later by outlin)
    int* deg     = (int*)d_out;
    int* cursor  = deg + N;
    int* row_ptr = cursor + N;
    int* eidx    = row_ptr + N + 1;

    float* m = (float*)d_ws;             // N*704 f32 = 140.8 MB

    (void)hipMemsetAsync(deg, 0, (size_t)2 * N * sizeof(int), stream);
    (void)hipMemsetAsync(m, 0, (size_t)N * MPN * sizeof(float), stream);

    const int eb = (E + 255) / 256;
    hist_kernel<<<eb, 256, 0, stream>>>(rcv, deg, E);
    scan_kernel<<<1, 256, 0, stream>>>(deg, row_ptr, N);
    fill_kernel<<<eb, 256, 0, stream>>>(rcv, row_ptr, cursor, eidx, E);

    self_kernel<<<(N + 3) / 4, 256, 0, stream>>>(fs, fv, Wes, Wev, out, N);

    const int nbe = (E + TEB - 1) / TEB;
    edge_kernel<<<nbe, 128, 0, stream>>>(ef, sh0, sh1, snd, rcv,
                                         W1, W2, W3, W4, s_st, v_st,
                                         eidx, m, E);

    dim3 g_out((N + 63) / 64, 4);
    outlin_kernel<<<g_out, 256, 0, stream>>>(m, Wos, Wov, out, N);

    dim3 g_sc((N + 63) / 64, 4);
    sc_kernel<<<g_sc, 256, 0, stream>>>(attrs, fs, fv, Wss, Wsv, out, N);
}

// Round 7
// 1072.797 us; speedup vs baseline: 2.6021x; 1.1303x over previous
//
#include <hip/hip_runtime.h>

#define NC    64      // channels C
#define NATTR 10      // node attrs
#define NH    64      // radial MLP hidden
#define NRAD  8       // radial features
#define TEB   128     // CSR positions per edge block
#define MPN   704     // f32 message floats per node

__device__ __forceinline__ float silu_f(float x) { return x / (1.0f + __expf(-x)); }

// ---------------- f16x2 pack helpers + hardware dot2 ----------------------
typedef __fp16 h2v __attribute__((ext_vector_type(2)));

__device__ __forceinline__ unsigned int pkh(float lo, float hi)
{
    union { h2v h; unsigned int u; } cv;
    cv.h = __builtin_amdgcn_cvt_pkrtz(lo, hi);   // v_cvt_pkrtz_f16_f32
    return cv.u;
}
__device__ __forceinline__ h2v uph(unsigned int u)
{
    union { unsigned int u; h2v h; } cv;
    cv.u = u;
    return cv.h;
}

#if defined(__has_builtin)
#if __has_builtin(__builtin_amdgcn_fdot2)
#define HAS_FDOT2 1
#endif
#endif

__device__ __forceinline__ float fd2(unsigned int a, unsigned int b, float c)
{
#ifdef HAS_FDOT2
    return __builtin_amdgcn_fdot2(uph(a), uph(b), c, false);  // v_dot2_f32_f16
#else
    h2v x = uph(a), y = uph(b);
    return c + (float)x[0] * (float)y[0] + (float)x[1] * (float)y[1];
#endif
}

// dual / triple dot of one packed-f16 h row (32 uints = 64 values) against
// register-resident W column slices. One LDS uint4 sweep feeds all dots.
__device__ __forceinline__ void dot2w(const uint4* hp,
    const unsigned int (&Wa)[32], const unsigned int (&Wb)[32],
    float& ra, float& rb)
{
    float a = 0.f, b = 0.f;
    #pragma unroll
    for (int q8 = 0; q8 < 8; q8++) {
        uint4 hu = hp[q8];
        unsigned int hw[4] = {hu.x, hu.y, hu.z, hu.w};
        #pragma unroll
        for (int k = 0; k < 4; k++) {
            a = fd2(hw[k], Wa[q8 * 4 + k], a);
            b = fd2(hw[k], Wb[q8 * 4 + k], b);
        }
    }
    ra = a * 0.125f; rb = b * 0.125f;   // 1/sqrt(64)
}

__device__ __forceinline__ void dot3w(const uint4* hp,
    const unsigned int (&Wa)[32], const unsigned int (&Wb)[32],
    const unsigned int (&Wc)[32],
    float& ra, float& rb, float& rc)
{
    float a = 0.f, b = 0.f, c = 0.f;
    #pragma unroll
    for (int q8 = 0; q8 < 8; q8++) {
        uint4 hu = hp[q8];
        unsigned int hw[4] = {hu.x, hu.y, hu.z, hu.w};
        #pragma unroll
        for (int k = 0; k < 4; k++) {
            a = fd2(hw[k], Wa[q8 * 4 + k], a);
            b = fd2(hw[k], Wb[q8 * 4 + k], b);
            c = fd2(hw[k], Wc[q8 * 4 + k], c);
        }
    }
    ra = a * 0.125f; rb = b * 0.125f; rc = c * 0.125f;
}

// ---------------------------------------------------------------------------
// d_out layout (f32, out_size = N*512):
//   out_s : [0,      N*64 )   -- also CSR int scratch until out written
//   out_v : [N*64,   N*256)
//   sc_s  : [N*256,  N*320)   -- self-linear s scratch until sc_kernel
//   sc_v  : [N*320,  N*512)   -- self-linear v scratch until sc_kernel
// ws: m[N*704] f32 message accumulator (140.8 MB)
// ---------------------------------------------------------------------------

// ---------------- CSR build (scratch ints live in d_out's out region) ------
__global__ void hist_kernel(const int* __restrict__ rcv, int* __restrict__ deg, int E)
{
    int e = blockIdx.x * 256 + threadIdx.x;
    if (e < E) atomicAdd(&deg[rcv[e]], 1);
}

__global__ __launch_bounds__(256)
void scan_kernel(const int* __restrict__ deg, int* __restrict__ row_ptr, int N)
{
    __shared__ int sums[256];
    __shared__ int offs[257];
    const int t = threadIdx.x;
    const int chunk = (N + 255) / 256;
    int b = t * chunk, e = min(N, b + chunk);
    int s = 0;
    for (int k = b; k < e; k++) s += deg[k];
    sums[t] = s;
    __syncthreads();
    if (t == 0) {
        int run = 0;
        for (int i = 0; i < 256; i++) { offs[i] = run; run += sums[i]; }
        offs[256] = run;
    }
    __syncthreads();
    int run = offs[t];
    for (int k = b; k < e; k++) { row_ptr[k] = run; run += deg[k]; }
    if (t == 255) row_ptr[N] = offs[256];
}

__global__ void fill_kernel(const int* __restrict__ rcv, const int* __restrict__ row_ptr,
                            int* __restrict__ cursor, int* __restrict__ eidx, int E)
{
    int e = blockIdx.x * 256 + threadIdx.x;
    if (e < E) {
        int r = rcv[e];
        int pos = atomicAdd(&cursor[r], 1);
        eidx[row_ptr[r] + pos] = e;
    }
}

// ---------------- self linear: wave-per-node, 4 nodes/block ----------------
__global__ __launch_bounds__(256)
void self_kernel(const float* __restrict__ fs, const float* __restrict__ fv,
                 const float* __restrict__ Wes, const float* __restrict__ Wev,
                 float* __restrict__ out, int N)
{
    __shared__ float s_l[4][NC];
    __shared__ float v_l[4][3][NC];
    const int t = threadIdx.x, wv = t >> 6, lane = t & 63;
    const int n = blockIdx.x * 4 + wv;

    if (n < N) {
        s_l[wv][lane] = fs[(size_t)n * NC + lane];
        v_l[wv][0][lane] = fv[(size_t)n * NC * 3 + lane * 3 + 0];
        v_l[wv][1][lane] = fv[(size_t)n * NC * 3 + lane * 3 + 1];
        v_l[wv][2][lane] = fv[(size_t)n * NC * 3 + lane * 3 + 2];
    }
    __syncthreads();
    if (n >= N) return;

    const int d = lane;
    float a = 0.f, bx = 0.f, by = 0.f, bz = 0.f;
    #pragma unroll 8
    for (int c = 0; c < NC; c++) {
        float ws = Wes[c * NC + d];
        float wvv = Wev[c * NC + d];
        a  += s_l[wv][c] * ws;
        bx += v_l[wv][0][c] * wvv;
        by += v_l[wv][1][c] * wvv;
        bz += v_l[wv][2][c] * wvv;
    }
    out[(size_t)N * 256 + (size_t)n * NC + d]            = a  * 0.125f;
    out[(size_t)N * 320 + (size_t)n * 192 +       d]     = bx * 0.125f;
    out[(size_t)N * 320 + (size_t)n * 192 +  64 + d]     = by * 0.125f;
    out[(size_t)N * 320 + (size_t)n * 192 + 128 + d]     = bz * 0.125f;
}

// ---------------------------------------------------------------------------
// Edge kernel: 128 CSR positions per 128-thread block.
// Phase 1: thread-per-edge radial MLP; h3 packed f16x2 -> LDS (21.5 KB).
// Phase 2: TWO fused passes (r6 had five single-slice passes):
//     A: slices {0,2} p1,p3 -- ONE se gather, 64 W-uints
//     B: slices {1,3,4} p2,p4,p5 -- ONE v gather, 96 W-uints
//   W register sets pinned with an asm identity so the compiler cannot
//   rematerialize the W4 loads inside the loop (r4/r6 VGPR=60..84 signature).
//   Depth-4 named-scalar gather prefetch under full unroll-4 (rotation is
//   pure renaming). CSR receiver-run register accumulation, atomic flush on
//   receiver change only.
// m per-node layout: [0,64) p1 | [64,128) p2 | 128 + x*192 + {0:p3,64:p4,128:p5}
// ---------------------------------------------------------------------------
__global__ __launch_bounds__(128, 3)
void edge_kernel(const float* __restrict__ ef, const float* __restrict__ sh0,
                 const float* __restrict__ sh1,
                 const int* __restrict__ snd, const int* __restrict__ rcv,
                 const float* __restrict__ W1, const float* __restrict__ W2,
                 const float* __restrict__ W3, const float* __restrict__ W4,
                 const float* __restrict__ s_st, const float* __restrict__ v_st,
                 const int* __restrict__ eidx,
                 float* __restrict__ m, int E)
{
    __shared__ unsigned int h_l[TEB][36];   // 32 packed f16x2 + pad (144B rows)
    __shared__ float sh1_l[TEB][3];
    __shared__ float sh0_l[TEB];
    __shared__ int   snd_l[TEB];
    __shared__ int   rcv_l[TEB];

    const int t = threadIdx.x;
    const int p0 = blockIdx.x * TEB;

    // ---------------- phase 1 ----------------
    {
        int p = p0 + t;
        bool valid = p < E;
        int e = valid ? eidx[p] : 0;
        snd_l[t] = valid ? snd[e] : 0;
        rcv_l[t] = valid ? rcv[e] : -1;
        sh0_l[t] = valid ? sh0[e] : 0.f;
        sh1_l[t][0] = valid ? sh1[(size_t)e * 3 + 0] : 0.f;
        sh1_l[t][1] = valid ? sh1[(size_t)e * 3 + 1] : 0.f;
        sh1_l[t][2] = valid ? sh1[(size_t)e * 3 + 2] : 0.f;

        float x[NRAD];
        #pragma unroll
        for (int r = 0; r < NRAD; r++)
            x[r] = valid ? ef[(size_t)e * NRAD + r] : 0.f;

        // layer 1: 8 -> 64 (h1 in registers)
        float h1[NH];
        #pragma unroll
        for (int j = 0; j < NH; j++) {
            float a = 0.f;
            #pragma unroll
            for (int r = 0; r < NRAD; r++) a += x[r] * W1[r * NH + j];
            h1[j] = silu_f(a * 0.35355339059327373f);   // 1/sqrt(8)
        }

        // layer 2: h1(f32 regs) -> h2 packed f16 (32 uint regs)
        unsigned int h2p[32];
        for (int jt = 0; jt < 16; jt++) {
            float a0 = 0.f, a1 = 0.f, a2 = 0.f, a3 = 0.f;
            #pragma unroll
            for (int c = 0; c < NH; c++) {
                float hv = h1[c];
                const float* wr = W2 + c * NH + jt * 4;
                a0 += hv * wr[0]; a1 += hv * wr[1];
                a2 += hv * wr[2]; a3 += hv * wr[3];
            }
            h2p[jt * 2 + 0] = pkh(silu_f(a0 * 0.125f), silu_f(a1 * 0.125f));
            h2p[jt * 2 + 1] = pkh(silu_f(a2 * 0.125f), silu_f(a3 * 0.125f));
        }
        // layer 3: h2 packed -> h3 packed -> LDS (h1 dead; regs reused)
        for (int jt = 0; jt < 16; jt++) {
            float a0 = 0.f, a1 = 0.f, a2 = 0.f, a3 = 0.f;
            #pragma unroll
            for (int cp = 0; cp < 32; cp++) {
                h2v u = uph(h2p[cp]);
                float hl = (float)u[0], hh = (float)u[1];
                const float* wr0 = W3 + (2 * cp) * NH + jt * 4;
                const float* wr1 = W3 + (2 * cp + 1) * NH + jt * 4;
                a0 += hl * wr0[0] + hh * wr1[0];
                a1 += hl * wr0[1] + hh * wr1[1];
                a2 += hl * wr0[2] + hh * wr1[2];
                a3 += hl * wr0[3] + hh * wr1[3];
            }
            h_l[t][jt * 2 + 0] = pkh(silu_f(a0 * 0.125f), silu_f(a1 * 0.125f));
            h_l[t][jt * 2 + 1] = pkh(silu_f(a2 * 0.125f), silu_f(a3 * 0.125f));
        }
    }
    __syncthreads();

    // ---------------- phase 2 ----------------
    const int wv = t >> 6, lane = t & 63;
    const int base = wv * 64;
    const int v_sd = snd_l[base + lane];   // sender of edge i in lane i
    const int v_rc = rcv_l[base + lane];   // receiver of edge i in lane i

    // ---- pass A: slices {0,2} -> p1,p3; one se gather per edge ------------
    {
        unsigned int WA[32], WC[32];
        #pragma unroll
        for (int q = 0; q < 32; q++) {
            WA[q] = pkh(W4[(2 * q) * 320 + lane],       W4[(2 * q + 1) * 320 + lane]);
            WC[q] = pkh(W4[(2 * q) * 320 + 128 + lane], W4[(2 * q + 1) * 320 + 128 + lane]);
        }
        // pin: value becomes asm-defined -> no remat of the global loads
        #pragma unroll
        for (int q = 0; q < 32; q++) {
            asm volatile("" : "+v"(WA[q]));
            asm volatile("" : "+v"(WC[q]));
        }
        float g0 = s_st[(size_t)__builtin_amdgcn_readlane(v_sd, 0) * NC + lane];
        float g1 = s_st[(size_t)__builtin_amdgcn_readlane(v_sd, 1) * NC + lane];
        float g2 = s_st[(size_t)__builtin_amdgcn_readlane(v_sd, 2) * NC + lane];
        float g3 = s_st[(size_t)__builtin_amdgcn_readlane(v_sd, 3) * NC + lane];
        int r_cur = -1;
        float a1 = 0.f, a3x = 0.f, a3y = 0.f, a3z = 0.f;
        #pragma unroll 4
        for (int ei = 0; ei < 64; ei++) {
            const int pn = (ei + 4 > 63) ? 63 : ei + 4;
            const float gf = s_st[(size_t)__builtin_amdgcn_readlane(v_sd, pn) * NC + lane];
            const int r = __builtin_amdgcn_readlane(v_rc, ei);
            if (r != r_cur) {
                if (r_cur >= 0) {
                    float* mb = m + (size_t)r_cur * MPN;
                    unsafeAtomicAdd(mb + lane,             a1);
                    unsafeAtomicAdd(mb + 128 + lane,       a3x);
                    unsafeAtomicAdd(mb + 128 + 192 + lane, a3y);
                    unsafeAtomicAdd(mb + 128 + 384 + lane, a3z);
                    a1 = a3x = a3y = a3z = 0.f;
                }
                r_cur = r;
            }
            if (r >= 0) {
                const int pos = base + ei;
                float w1w, w3w;
                dot2w((const uint4*)(&h_l[pos][0]), WA, WC, w1w, w3w);
                float se = g0;
                a1 += w1w * se * sh0_l[pos];
                float t3 = w3w * se;
                a3x += t3 * sh1_l[pos][0];
                a3y += t3 * sh1_l[pos][1];
                a3z += t3 * sh1_l[pos][2];
            }
            g0 = g1; g1 = g2; g2 = g3; g3 = gf;
        }
        if (r_cur >= 0) {
            float* mb = m + (size_t)r_cur * MPN;
            unsafeAtomicAdd(mb + lane,             a1);
            unsafeAtomicAdd(mb + 128 + lane,       a3x);
            unsafeAtomicAdd(mb + 128 + 192 + lane, a3y);
            unsafeAtomicAdd(mb + 128 + 384 + lane, a3z);
        }
    }

    // ---- pass B: slices {1,3,4} -> p2,p4,p5; one v gather per edge --------
    {
        unsigned int WB[32], WD[32], WE[32];
        #pragma unroll
        for (int q = 0; q < 32; q++) {
            WB[q] = pkh(W4[(2 * q) * 320 +  64 + lane], W4[(2 * q + 1) * 320 +  64 + lane]);
            WD[q] = pkh(W4[(2 * q) * 320 + 192 + lane], W4[(2 * q + 1) * 320 + 192 + lane]);
            WE[q] = pkh(W4[(2 * q) * 320 + 256 + lane], W4[(2 * q + 1) * 320 + 256 + lane]);
        }
        #pragma unroll
        for (int q = 0; q < 32; q++) {
            asm volatile("" : "+v"(WB[q]));
            asm volatile("" : "+v"(WD[q]));
            asm volatile("" : "+v"(WE[q]));
        }
        float gx0, gy0, gz0, gx1, gy1, gz1, gx2, gy2, gz2, gx3, gy3, gz3;
        {
            size_t s0 = (size_t)__builtin_amdgcn_readlane(v_sd, 0) * 192;
            size_t s1 = (size_t)__builtin_amdgcn_readlane(v_sd, 1) * 192;
            size_t s2 = (size_t)__builtin_amdgcn_readlane(v_sd, 2) * 192;
            size_t s3 = (size_t)__builtin_amdgcn_readlane(v_sd, 3) * 192;
            gx0 = v_st[s0 + lane]; gy0 = v_st[s0 + 64 + lane]; gz0 = v_st[s0 + 128 + lane];
            gx1 = v_st[s1 + lane]; gy1 = v_st[s1 + 64 + lane]; gz1 = v_st[s1 + 128 + lane];
            gx2 = v_st[s2 + lane]; gy2 = v_st[s2 + 64 + lane]; gz2 = v_st[s2 + 128 + lane];
            gx3 = v_st[s3 + lane]; gy3 = v_st[s3 + 64 + lane]; gz3 = v_st[s3 + 128 + lane];
        }
        int r_cur = -1;
        float a2 = 0.f;
        float a4x = 0.f, a4y = 0.f, a4z = 0.f;
        float a5x = 0.f, a5y = 0.f, a5z = 0.f;
        #pragma unroll 4
        for (int ei = 0; ei < 64; ei++) {
            const int pn = (ei + 4 > 63) ? 63 : ei + 4;
            size_t sb = (size_t)__builtin_amdgcn_readlane(v_sd, pn) * 192;
            const float gxf = v_st[sb + lane];
            const float gyf = v_st[sb + 64 + lane];
            const float gzf = v_st[sb + 128 + lane];
            const int r = __builtin_amdgcn_readlane(v_rc, ei);
            if (r != r_cur) {
                if (r_cur >= 0) {
                    float* mb = m + (size_t)r_cur * MPN;
                    unsafeAtomicAdd(mb + 64 + lane,              a2);
                    unsafeAtomicAdd(mb + 128 + 64 + lane,        a4x);
                    unsafeAtomicAdd(mb + 128 + 192 + 64 + lane,  a4y);
                    unsafeAtomicAdd(mb + 128 + 384 + 64 + lane,  a4z);
                    unsafeAtomicAdd(mb + 128 + 128 + lane,       a5x);
                    unsafeAtomicAdd(mb + 128 + 192 + 128 + lane, a5y);
                    unsafeAtomicAdd(mb + 128 + 384 + 128 + lane, a5z);
                    a2 = a4x = a4y = a4z = a5x = a5y = a5z = 0.f;
                }
                r_cur = r;
            }
            if (r >= 0) {
                const int pos = base + ei;
                float w2w, w4w, w5w;
                dot3w((const uint4*)(&h_l[pos][0]), WB, WD, WE, w2w, w4w, w5w);
                float vx = gx0, vy = gy0, vz = gz0;
                float shx = sh1_l[pos][0], shy = sh1_l[pos][1], shz = sh1_l[pos][2];
                float dot = vx * shx + vy * shy + vz * shz;
                a2 += w2w * dot * 0.5773502691896258f;   // 1/sqrt(3)
                float w4s = w4w * sh0_l[pos];
                a4x += w4s * vx; a4y += w4s * vy; a4z += w4s * vz;
                float w5s = w5w * 0.7071067811865476f;   // 1/sqrt(2)
                a5x += w5s * (vy * shz - vz * shy);
                a5y += w5s * (vz * shx - vx * shz);
                a5z += w5s * (vx * shy - vy * shx);
            }
            gx0 = gx1; gy0 = gy1; gz0 = gz1;
            gx1 = gx2; gy1 = gy2; gz1 = gz2;
            gx2 = gx3; gy2 = gy3; gz2 = gz3;
            gx3 = gxf; gy3 = gyf; gz3 = gzf;
        }
        if (r_cur >= 0) {
            float* mb = m + (size_t)r_cur * MPN;
            unsafeAtomicAdd(mb + 64 + lane,              a2);
            unsafeAtomicAdd(mb + 128 + 64 + lane,        a4x);
            unsafeAtomicAdd(mb + 128 + 192 + 64 + lane,  a4y);
            unsafeAtomicAdd(mb + 128 + 384 + 64 + lane,  a4z);
            unsafeAtomicAdd(mb + 128 + 128 + lane,       a5x);
            unsafeAtomicAdd(mb + 128 + 192 + 128 + lane, a5y);
            unsafeAtomicAdd(mb + 128 + 384 + 128 + lane, a5z);
        }
    }
}

// ---------------------------------------------------------------------------
// Skip-connection as tiled GEMM with f16x2-packed LDS tiles + v_dot2_f32_f16.
// C[64n x 64d] per block, A[n][k]=feat*attr built on the fly, 4x4 register
// blocking, f32 accumulation. blockIdx.y = part (0: scalar, 1..3: vector x).
// ---------------------------------------------------------------------------
__global__ __launch_bounds__(256)
void sc_kernel(const float* __restrict__ attrs, const float* __restrict__ fs,
               const float* __restrict__ fv,
               const float* __restrict__ Wss, const float* __restrict__ Wsv,
               float* __restrict__ out, int N)
{
    __shared__ unsigned int At[32][68];   // [k-pair][n] f16x2
    __shared__ unsigned int Bt[32][68];   // [k-pair][d] f16x2

    const int part = blockIdx.y;
    const int n0 = blockIdx.x * 64;
    const int t = threadIdx.x;
    const int tn = t & 15, td = t >> 4;
    const float* W = (part == 0) ? Wss : Wsv;
    const int x = part - 1;

    float acc[4][4];
    #pragma unroll
    for (int i = 0; i < 4; i++)
        #pragma unroll
        for (int j = 0; j < 4; j++) acc[i][j] = 0.f;

    for (int kt = 0; kt < 10; kt++) {
        __syncthreads();
        // build A-tile (packed k-pairs)
        for (int i = t; i < 2048; i += 256) {
            int n = i >> 5, kp = i & 31;
            int k0 = kt * 64 + kp * 2;
            int c0 = k0 / 10, a0 = k0 - c0 * 10;
            int k1 = k0 + 1;
            int c1 = k1 / 10, a1 = k1 - c1 * 10;
            int ng = n0 + n;
            float f0 = 0.f, f1 = 0.f;
            if (ng < N) {
                float fa = (part == 0) ? fs[(size_t)ng * 64 + c0]
                                       : fv[((size_t)ng * 64 + c0) * 3 + x];
                float fb = (part == 0) ? fs[(size_t)ng * 64 + c1]
                                       : fv[((size_t)ng * 64 + c1) * 3 + x];
                f0 = fa * attrs[(size_t)ng * 10 + a0];
                f1 = fb * attrs[(size_t)ng * 10 + a1];
            }
            At[kp][n] = pkh(f0, f1);
        }
        // load B-tile (packed k-pairs, coalesced in d)
        for (int i = t; i < 2048; i += 256) {
            int kp = i >> 6, d = i & 63;
            Bt[kp][d] = pkh(W[(size_t)(kt * 64 + 2 * kp) * 64 + d],
                            W[(size_t)(kt * 64 + 2 * kp + 1) * 64 + d]);
        }
        __syncthreads();
        #pragma unroll 8
        for (int kp = 0; kp < 32; kp++) {
            uint4 au = *(const uint4*)(&At[kp][tn * 4]);
            uint4 bu = *(const uint4*)(&Bt[kp][td * 4]);
            unsigned int aa[4] = {au.x, au.y, au.z, au.w};
            unsigned int bb[4] = {bu.x, bu.y, bu.z, bu.w};
            #pragma unroll
            for (int i = 0; i < 4; i++)
                #pragma unroll
                for (int j = 0; j < 4; j++)
                    acc[i][j] = fd2(aa[i], bb[j], acc[i][j]);
        }
    }

    const float inv_sc = 0.03952847075210474f;  // 1/sqrt(640)
    #pragma unroll
    for (int i = 0; i < 4; i++) {
        int ng = n0 + tn * 4 + i;
        if (ng >= N) continue;
        #pragma unroll
        for (int j = 0; j < 4; j++) {
            int d = td * 4 + j;
            float v = acc[i][j] * inv_sc;
            if (part == 0) out[(size_t)N * 256 + (size_t)ng * 64 + d] = v;
            else           out[(size_t)N * 320 + (size_t)ng * 192 + d * 3 + x] = v;
        }
    }
}

// ---------------------------------------------------------------------------
// Output linear as tiled GEMM over m, f16x2-packed + v_dot2_f32_f16.
// blockIdx.y = part (0: scalar k=128, 1..3: vector x, k=192).
// ---------------------------------------------------------------------------
__global__ __launch_bounds__(256)
void outlin_kernel(const float* __restrict__ m,
                   const float* __restrict__ Wos, const float* __restrict__ Wov,
                   float* __restrict__ out, int N)
{
    __shared__ unsigned int At[32][68];
    __shared__ unsigned int Bt[32][68];

    const int part = blockIdx.y;
    const int n0 = blockIdx.x * 64;
    const int t = threadIdx.x;
    const int tn = t & 15, td = t >> 4;
    const int x = part - 1;
    const int ntiles = (part == 0) ? 2 : 3;
    const int aoff = (part == 0) ? 0 : 128 + x * 192;
    const float* W = (part == 0) ? Wos : Wov;

    float acc[4][4];
    #pragma unroll
    for (int i = 0; i < 4; i++)
        #pragma unroll
        for (int j = 0; j < 4; j++) acc[i][j] = 0.f;

    for (int kt = 0; kt < ntiles; kt++) {
        __syncthreads();
        for (int i = t; i < 2048; i += 256) {
            int n = i >> 5, kp = i & 31;
            int ng = n0 + n;
            float f0 = 0.f, f1 = 0.f;
            if (ng < N) {
                const float* mp = m + (size_t)ng * MPN + aoff + kt * 64 + kp * 2;
                f0 = mp[0]; f1 = mp[1];
            }
            At[kp][n] = pkh(f0, f1);
        }
        for (int i = t; i < 2048; i += 256) {
            int kp = i >> 6, d = i & 63;
            Bt[kp][d] = pkh(W[(size_t)(kt * 64 + 2 * kp) * 64 + d],
                            W[(size_t)(kt * 64 + 2 * kp + 1) * 64 + d]);
        }
        __syncthreads();
        #pragma unroll 8
        for (int kp = 0; kp < 32; kp++) {
            uint4 au = *(const uint4*)(&At[kp][tn * 4]);
            uint4 bu = *(const uint4*)(&Bt[kp][td * 4]);
            unsigned int aa[4] = {au.x, au.y, au.z, au.w};
            unsigned int bb[4] = {bu.x, bu.y, bu.z, bu.w};
            #pragma unroll
            for (int i = 0; i < 4; i++)
                #pragma unroll
                for (int j = 0; j < 4; j++)
                    acc[i][j] = fd2(aa[i], bb[j], acc[i][j]);
        }
    }

    const float scale = (part == 0) ? 0.005524271728019903f    // 1/(sqrt(128)*16)
                                    : 0.004510527174164819f;   // 1/(sqrt(192)*16)
    #pragma unroll
    for (int i = 0; i < 4; i++) {
        int ng = n0 + tn * 4 + i;
        if (ng >= N) continue;
        #pragma unroll
        for (int j = 0; j < 4; j++) {
            int d = td * 4 + j;
            float v = acc[i][j] * scale;
            if (part == 0) out[(size_t)ng * 64 + d] = v;
            else           out[(size_t)N * 64 + (size_t)ng * 192 + d * 3 + x] = v;
        }
    }
}

// ---------------------------------------------------------------------------
extern "C" void kernel_launch(void* const* d_in, const int* in_sizes, int n_in,
                              void* d_out, int out_size, void* d_ws, size_t ws_size,
                              hipStream_t stream)
{
    const float* attrs = (const float*)d_in[0];
    const float* fs    = (const float*)d_in[1];
    const float* fv    = (const float*)d_in[2];
    const float* sh0   = (const float*)d_in[3];
    const float* sh1   = (const float*)d_in[4];
    const float* ef    = (const float*)d_in[5];
    const int*   snd   = (const int*)d_in[6];
    const int*   rcv   = (const int*)d_in[7];
    const float* Wss   = (const float*)d_in[8];
    const float* Wsv   = (const float*)d_in[9];
    const float* Wes   = (const float*)d_in[10];
    const float* Wev   = (const float*)d_in[11];
    const float* W1    = (const float*)d_in[12];
    const float* W2    = (const float*)d_in[13];
    const float* W3    = (const float*)d_in[14];
    const float* W4    = (const float*)d_in[15];
    const float* Wos   = (const float*)d_in[16];
    const float* Wov   = (const float*)d_in[17];

    const int N = in_sizes[0] / NATTR;   // 50000
    const int E = in_sizes[6];           // 320000

    float* out = (float*)d_out;
    const float* s_st = out + (size_t)N * 256;  // self-linear s scratch
    const float* v_st = out + (size_t)N * 320;  // self-linear v scratch

    // CSR int scratch in d_out's out region (overwritten later by outlin)
    int* deg     = (int*)d_out;
    int* cursor  = deg + N;
    int* row_ptr = cursor + N;
    int* eidx    = row_ptr + N + 1;

    float* m = (float*)d_ws;             // N*704 f32 = 140.8 MB

    (void)hipMemsetAsync(deg, 0, (size_t)2 * N * sizeof(int), stream);
    (void)hipMemsetAsync(m, 0, (size_t)N * MPN * sizeof(float), stream);

    const int eb = (E + 255) / 256;
    hist_kernel<<<eb, 256, 0, stream>>>(rcv, deg, E);
    scan_kernel<<<1, 256, 0, stream>>>(deg, row_ptr, N);
    fill_kernel<<<eb, 256, 0, stream>>>(rcv, row_ptr, cursor, eidx, E);

    self_kernel<<<(N + 3) / 4, 256, 0, stream>>>(fs, fv, Wes, Wev, out, N);

    const int nbe = (E + TEB - 1) / TEB;
    edge_kernel<<<nbe, 128, 0, stream>>>(ef, sh0, sh1, snd, rcv,
                                         W1, W2, W3, W4, s_st, v_st,
                                         eidx, m, E);

    dim3 g_out((N + 63) / 64, 4);
    outlin_kernel<<<g_out, 256, 0, stream>>>(m, Wos, Wov, out, N);

    dim3 g_sc((N + 63) / 64, 4);
    sc_kernel<<<g_sc, 256, 0, stream>>>(attrs, fs, fv, Wss, Wsv, out, N);
}